// Round 1
// baseline (792.181 us; speedup 1.0000x reference)
//
#include <hip/hip_runtime.h>
#include <hip/hip_bf16.h>
#include <math.h>

// ---------- helpers ----------
typedef __attribute__((ext_vector_type(8))) short short8;   // 8 bf16 = 4 VGPR (MFMA A/B frag)
typedef __attribute__((ext_vector_type(4))) float f32x4;    // MFMA C/D frag

__device__ __forceinline__ unsigned short f2b(float x) {    // fp32 -> bf16 bits, RNE
  union { float f; unsigned int u; } v; v.f = x;
  unsigned int r = v.u + 0x7fffu + ((v.u >> 16) & 1u);
  return (unsigned short)(r >> 16);
}
__device__ __forceinline__ float b2f(unsigned short u) {
  union { unsigned int u; float f; } v; v.u = ((unsigned int)u) << 16;
  return v.f;
}
__device__ __forceinline__ void async_ld16(const void* g, void* l) {
  // global -> LDS direct copy, 16B/lane. LDS dst is wave-uniform base + lane*16.
  __builtin_amdgcn_global_load_lds(
      (const __attribute__((address_space(1))) void*)g,
      (__attribute__((address_space(3))) void*)l, 16, 0, 0);
}

// ---------- prep: dt mean, A_bar = expm(A*mdt) via Taylor, A64 = A_bar^64 ----------
__global__ __launch_bounds__(256) void prep_kernel(
    const float* __restrict__ A, const float* __restrict__ logdt,
    float* __restrict__ Abar, float* __restrict__ A64) {
  __shared__ float red[256];
  const int tid = threadIdx.x;
  float lsum = 0.f;
  for (int k = tid; k < 1024; k += 256) lsum += expf(logdt[k]);
  red[tid] = lsum; __syncthreads();
  for (int s = 128; s > 0; s >>= 1) { if (tid < s) red[tid] += red[tid + s]; __syncthreads(); }
  const float mdt = red[0] * (1.f / 1024.f);

  __shared__ float Ms[4096], T[4096], Tn[4096], P[4096];
  for (int e = tid; e < 4096; e += 256) {
    float m = A[e] * mdt;
    Ms[e] = m; T[e] = m;
    P[e] = m + (((e >> 6) == (e & 63)) ? 1.f : 0.f);
  }
  __syncthreads();
  for (int k = 2; k <= 8; k++) {            // Taylor: P = I + M + M^2/2! + ...
    const float inv = 1.f / (float)k;
    for (int e = tid; e < 4096; e += 256) {
      int r = e >> 6, c = e & 63; float acc = 0.f;
      for (int j = 0; j < 64; j++) acc += T[r * 64 + j] * Ms[j * 64 + c];
      Tn[e] = acc * inv;
    }
    __syncthreads();
    for (int e = tid; e < 4096; e += 256) { T[e] = Tn[e]; P[e] += Tn[e]; }
    __syncthreads();
  }
  for (int e = tid; e < 4096; e += 256) { Abar[e] = P[e]; T[e] = P[e]; }
  __syncthreads();
  for (int sq = 0; sq < 6; sq++) {          // A64 = Abar^(2^6)
    for (int e = tid; e < 4096; e += 256) {
      int r = e >> 6, c = e & 63; float acc = 0.f;
      for (int j = 0; j < 64; j++) acc += T[r * 64 + j] * T[j * 64 + c];
      Tn[e] = acc;
    }
    __syncthreads();
    for (int e = tid; e < 4096; e += 256) T[e] = Tn[e];
    __syncthreads();
  }
  for (int e = tid; e < 4096; e += 256) A64[e] = T[e];
}

// ---------- fp32 -> bf16 weight conversions + B_bar = B * dt ----------
__global__ __launch_bounds__(256) void convert_all(
    const float* __restrict__ wg, const float* __restrict__ wu, const float* __restrict__ wd,
    const float* __restrict__ B, const float* __restrict__ C, const float* __restrict__ logdt,
    unsigned short* __restrict__ wgb, unsigned short* __restrict__ wub,
    unsigned short* __restrict__ wdb, unsigned short* __restrict__ Bb,
    unsigned short* __restrict__ Cb) {
  const size_t NW = (size_t)4096 * 1024;
  const size_t NB = (size_t)64 * 1024;
  const size_t NC = (size_t)1024 * 64;
  const size_t total = 3 * NW + NB + NC;
  for (size_t id = (size_t)blockIdx.x * blockDim.x + threadIdx.x; id < total;
       id += (size_t)gridDim.x * blockDim.x) {
    if (id < NW)            wgb[id] = f2b(wg[id]);
    else if (id < 2 * NW)   wub[id - NW] = f2b(wu[id - NW]);
    else if (id < 3 * NW)   wdb[id - 2 * NW] = f2b(wd[id - 2 * NW]);
    else if (id < 3 * NW + NB) {
      size_t e = id - 3 * NW; int k = (int)(e & 1023);
      Bb[e] = f2b(B[e] * expf(logdt[k]));
    } else {
      size_t e = id - 3 * NW - NB;
      Cb[e] = f2b(C[e]);
    }
  }
}

// ---------- RMSNorm (row = 1024) -> bf16 ----------
__global__ __launch_bounds__(256) void rmsnorm_bf16(
    const float* __restrict__ x, const float* __restrict__ w,
    unsigned short* __restrict__ out) {
  const size_t row = blockIdx.x;
  const int tid = threadIdx.x;
  const float4 v = ((const float4*)(x + row * 1024))[tid];
  float ss = v.x * v.x + v.y * v.y + v.z * v.z + v.w * v.w;
#pragma unroll
  for (int off = 32; off > 0; off >>= 1) ss += __shfl_down(ss, off);
  __shared__ float wsum[4];
  if ((tid & 63) == 0) wsum[tid >> 6] = ss;
  __syncthreads();
  const float tot = wsum[0] + wsum[1] + wsum[2] + wsum[3];
  const float rs = rsqrtf(tot * (1.f / 1024.f) + 1e-6f);
  const float4 wv = ((const float4*)w)[tid];
  ushort4 o;
  o.x = f2b(v.x * rs * wv.x); o.y = f2b(v.y * rs * wv.y);
  o.z = f2b(v.z * rs * wv.z); o.w = f2b(v.w * rs * wv.w);
  ((ushort4*)(out + row * 1024))[tid] = o;
}

// ---------- chunked scan: s_t = Abar s_{t-1} + u_t ----------
// STORE_S==0: zero-init, write chunk-end state. STORE_S==1: carry-init, write all states (bf16).
template <int STORE_S>
__global__ __launch_bounds__(64) void scan_chunk(
    const float* __restrict__ U, const float* __restrict__ Abar,
    const float* __restrict__ carry, float* __restrict__ zend,
    unsigned short* __restrict__ S) {
  const int b = blockIdx.y, c = blockIdx.x;
  const int i = threadIdx.x;
  float a[64];
#pragma unroll
  for (int j = 0; j < 64; j++) a[j] = Abar[i * 64 + j];
  __shared__ float s[64];
  s[i] = STORE_S ? carry[(b * 32 + c) * 64 + i] : 0.f;
  __syncthreads();
  const float* Ub = U + ((size_t)(b * 2048 + c * 64)) * 64;
  for (int t = 0; t < 64; t++) {
    const float u = Ub[t * 64 + i];
    const float4* s4 = (const float4*)s;
    float a0 = u, a1 = 0.f, a2 = 0.f, a3 = 0.f;
#pragma unroll
    for (int j = 0; j < 16; j++) {
      float4 v = s4[j];
      a0 += a[4 * j + 0] * v.x; a1 += a[4 * j + 1] * v.y;
      a2 += a[4 * j + 2] * v.z; a3 += a[4 * j + 3] * v.w;
    }
    const float sn = (a0 + a1) + (a2 + a3);
    __syncthreads();
    s[i] = sn;
    __syncthreads();
    if (STORE_S) S[((size_t)(b * 2048 + c * 64 + t)) * 64 + i] = f2b(sn);
  }
  if (!STORE_S) zend[(b * 32 + c) * 64 + i] = s[i];
}

// carry_c = end-state before chunk c:  e_{-1}=0; carry_c = e_{c-1}; e_c = A64 e_{c-1} + zend_c
__global__ __launch_bounds__(64) void scan_carry(
    const float* __restrict__ zend, const float* __restrict__ A64,
    float* __restrict__ carry) {
  const int b = blockIdx.x;
  const int i = threadIdx.x;
  float a[64];
#pragma unroll
  for (int j = 0; j < 64; j++) a[j] = A64[i * 64 + j];
  __shared__ float s[64];
  s[i] = 0.f;
  __syncthreads();
  for (int c = 0; c < 32; c++) {
    carry[(b * 32 + c) * 64 + i] = s[i];
    const float z = zend[(b * 32 + c) * 64 + i];
    const float4* s4 = (const float4*)s;
    float a0 = z, a1 = 0.f, a2 = 0.f, a3 = 0.f;
#pragma unroll
    for (int j = 0; j < 16; j++) {
      float4 v = s4[j];
      a0 += a[4 * j + 0] * v.x; a1 += a[4 * j + 1] * v.y;
      a2 += a[4 * j + 2] * v.z; a3 += a[4 * j + 3] * v.w;
    }
    const float sn = (a0 + a1) + (a2 + a3);
    __syncthreads();
    s[i] = sn;
    __syncthreads();
  }
}

// ---------- bf16 MFMA GEMM:  C(M,N) = X(M,K) @ W(N,K)^T, fused epilogues ----------
// EPI: 0 = fp32 store | 1 = bf16 store | 2 = silu(e_b)*acc -> bf16 | 3 = e_f + acc -> fp32
//      4 = acc + e_d[n]*bf(e_b) + e_f -> fp32   (SSM out + D*xn + residual)
template <int BM, int BN, int WAVES_M, int WAVES_N, int EPI>
__global__ void __launch_bounds__(256) gemm_bt(
    const unsigned short* __restrict__ X, const unsigned short* __restrict__ W,
    int M, int N, int K,
    float* __restrict__ outf, unsigned short* __restrict__ outb,
    const unsigned short* __restrict__ e_b, const float* __restrict__ e_f,
    const float* __restrict__ e_d) {
  constexpr int BK = 64;                       // 8 chunks of 16B per row
  constexpr int SM = BM / WAVES_M, SN = BN / WAVES_N;
  constexpr int TM = SM / 16, TN = SN / 16;
  __shared__ unsigned short aT[BM * BK];
  __shared__ unsigned short bT[BN * BK];
  const int tid = threadIdx.x;
  const int lane = tid & 63, wave = tid >> 6;
  const int wm = wave / WAVES_N, wn = wave % WAVES_N;
  const int lm = lane & 15, quad = lane >> 4;
  const long bm0 = (long)blockIdx.y * BM;
  const long bn0 = (long)blockIdx.x * BN;
  const int wb = tid & ~63;                    // wave-uniform slot base

  f32x4 acc[TM][TN];
#pragma unroll
  for (int i = 0; i < TM; i++)
#pragma unroll
    for (int j = 0; j < TN; j++) acc[i][j] = (f32x4){0.f, 0.f, 0.f, 0.f};

  for (int k0 = 0; k0 < K; k0 += BK) {
    // stage A,B tiles; LDS layout XOR-swizzled: slot(r,c') holds global chunk c = c'^(r&7)
#pragma unroll
    for (int it = 0; it < (BM * 8) / 256; ++it) {
      int slot = it * 256 + tid;
      int r = slot >> 3, cp = slot & 7, c = cp ^ (r & 7);
      async_ld16(X + (bm0 + r) * (long)K + k0 + c * 8, aT + (it * 256 + wb) * 8);
    }
#pragma unroll
    for (int it = 0; it < (BN * 8) / 256; ++it) {
      int slot = it * 256 + tid;
      int r = slot >> 3, cp = slot & 7, c = cp ^ (r & 7);
      async_ld16(W + (bn0 + r) * (long)K + k0 + c * 8, bT + (it * 256 + wb) * 8);
    }
    __syncthreads();
#pragma unroll
    for (int kk = 0; kk < BK; kk += 32) {
      const int cch = (kk >> 3) + quad;        // 16B chunk holding this lane's 8 k-values
      short8 af[TM], bf[TN];
#pragma unroll
      for (int i = 0; i < TM; i++) {
        int r = wm * SM + i * 16 + lm;
        af[i] = *(const short8*)(aT + (r * 8 + (cch ^ (r & 7))) * 8);
      }
#pragma unroll
      for (int j = 0; j < TN; j++) {
        int r = wn * SN + j * 16 + lm;
        bf[j] = *(const short8*)(bT + (r * 8 + (cch ^ (r & 7))) * 8);
      }
#pragma unroll
      for (int i = 0; i < TM; i++)
#pragma unroll
        for (int j = 0; j < TN; j++)
          acc[i][j] = __builtin_amdgcn_mfma_f32_16x16x32_bf16(af[i], bf[j], acc[i][j], 0, 0, 0);
    }
    __syncthreads();
  }
  // epilogue: C/D layout row = quad*4 + reg, col = lane&15
#pragma unroll
  for (int i = 0; i < TM; i++) {
#pragma unroll
    for (int j = 0; j < TN; j++) {
#pragma unroll
      for (int r = 0; r < 4; r++) {
        const long m = bm0 + wm * SM + i * 16 + quad * 4 + r;
        const long n = bn0 + wn * SN + j * 16 + lm;
        const long idx = m * N + n;
        const float v = acc[i][j][r];
        if (EPI == 0) {
          outf[idx] = v;
        } else if (EPI == 1) {
          outb[idx] = f2b(v);
        } else if (EPI == 2) {
          float g = b2f(e_b[idx]);
          float s = g / (1.f + __expf(-g));
          outb[idx] = f2b(s * v);
        } else if (EPI == 3) {
          outf[idx] = e_f[idx] + v;
        } else if (EPI == 4) {
          outf[idx] = v + e_d[n] * b2f(e_b[idx]) + e_f[idx];
        }
      }
    }
  }
}

// ---------- launch ----------
extern "C" void kernel_launch(void* const* d_in, const int* in_sizes, int n_in,
                              void* d_out, int out_size, void* d_ws, size_t ws_size,
                              hipStream_t stream) {
  const float* x     = (const float*)d_in[0];   // (4,2048,1024)
  const float* A     = (const float*)d_in[1];   // (64,64)
  const float* B     = (const float*)d_in[2];   // (64,1024)
  const float* C     = (const float*)d_in[3];   // (1024,64)
  const float* D     = (const float*)d_in[4];   // (1024,)
  const float* logdt = (const float*)d_in[5];   // (1024,)
  const float* wg    = (const float*)d_in[6];   // (4096,1024)
  const float* wu    = (const float*)d_in[7];   // (4096,1024)
  const float* wd    = (const float*)d_in[8];   // (1024,4096)
  const float* ln1   = (const float*)d_in[9];
  const float* ln2   = (const float*)d_in[10];
  float* out = (float*)d_out;

  char* p = (char*)d_ws;
  auto alloc = [&](size_t bytes) { char* q = p; p += (bytes + 255) & ~(size_t)255; return q; };
  float* Abar  = (float*)alloc(64 * 64 * 4);
  float* A64   = (float*)alloc(64 * 64 * 4);
  float* zend  = (float*)alloc(4 * 32 * 64 * 4);
  float* carry = (float*)alloc(4 * 32 * 64 * 4);
  float* U     = (float*)alloc((size_t)8192 * 64 * 4);
  unsigned short* S    = (unsigned short*)alloc((size_t)8192 * 64 * 2);
  unsigned short* Bb   = (unsigned short*)alloc((size_t)64 * 1024 * 2);
  unsigned short* Cb   = (unsigned short*)alloc((size_t)1024 * 64 * 2);
  unsigned short* wgb  = (unsigned short*)alloc((size_t)4096 * 1024 * 2);
  unsigned short* wub  = (unsigned short*)alloc((size_t)4096 * 1024 * 2);
  unsigned short* wdb  = (unsigned short*)alloc((size_t)1024 * 4096 * 2);
  unsigned short* xnb  = (unsigned short*)alloc((size_t)8192 * 1024 * 2);
  unsigned short* hnb  = (unsigned short*)alloc((size_t)8192 * 1024 * 2);
  float* h             = (float*)alloc((size_t)8192 * 1024 * 4);
  unsigned short* gateb = (unsigned short*)alloc((size_t)8192 * 4096 * 2);
  unsigned short* actb  = (unsigned short*)alloc((size_t)8192 * 4096 * 2);

  prep_kernel<<<1, 256, 0, stream>>>(A, logdt, Abar, A64);
  convert_all<<<4096, 256, 0, stream>>>(wg, wu, wd, B, C, logdt, wgb, wub, wdb, Bb, Cb);
  rmsnorm_bf16<<<8192, 256, 0, stream>>>(x, ln1, xnb);
  // U = xn @ B_bar^T   (8192x64)
  gemm_bt<128, 64, 4, 1, 0><<<dim3(1, 64), 256, 0, stream>>>(
      xnb, Bb, 8192, 64, 1024, U, nullptr, nullptr, nullptr, nullptr);
  // chunked linear scan
  scan_chunk<0><<<dim3(32, 4), 64, 0, stream>>>(U, Abar, carry, zend, S);
  scan_carry<<<4, 64, 0, stream>>>(zend, A64, carry);
  scan_chunk<1><<<dim3(32, 4), 64, 0, stream>>>(U, Abar, carry, zend, S);
  // h = S @ C^T + D*xn + x
  gemm_bt<128, 128, 2, 2, 4><<<dim3(8, 64), 256, 0, stream>>>(
      S, Cb, 8192, 1024, 64, h, nullptr, xnb, x, D);
  rmsnorm_bf16<<<8192, 256, 0, stream>>>(h, ln2, hnb);
  // gate = hn @ wg^T (bf16), act = silu(gate) * (hn @ wu^T) (bf16)
  gemm_bt<128, 128, 2, 2, 1><<<dim3(32, 64), 256, 0, stream>>>(
      hnb, wgb, 8192, 4096, 1024, nullptr, gateb, nullptr, nullptr, nullptr);
  gemm_bt<128, 128, 2, 2, 2><<<dim3(32, 64), 256, 0, stream>>>(
      hnb, wub, 8192, 4096, 1024, nullptr, actb, gateb, nullptr, nullptr);
  // out = h + act @ wd^T
  gemm_bt<128, 128, 2, 2, 3><<<dim3(8, 64), 256, 0, stream>>>(
      actb, wdb, 8192, 1024, 4096, out, nullptr, nullptr, h, nullptr);
}

// Round 2
// 622.961 us; speedup vs baseline: 1.2716x; 1.2716x over previous
//
#include <hip/hip_runtime.h>
#include <hip/hip_bf16.h>
#include <math.h>

// ---------- helpers ----------
typedef __attribute__((ext_vector_type(8))) short short8;   // 8 bf16 = 4 VGPR (MFMA A/B frag)
typedef __attribute__((ext_vector_type(4))) float f32x4;    // MFMA C/D frag

__device__ __forceinline__ unsigned short f2b(float x) {    // fp32 -> bf16 bits, RNE
  union { float f; unsigned int u; } v; v.f = x;
  unsigned int r = v.u + 0x7fffu + ((v.u >> 16) & 1u);
  return (unsigned short)(r >> 16);
}
__device__ __forceinline__ float b2f(unsigned short u) {
  union { unsigned int u; float f; } v; v.u = ((unsigned int)u) << 16;
  return v.f;
}
__device__ __forceinline__ void async_ld16(const void* g, void* l) {
  // global -> LDS direct copy, 16B/lane. LDS dst is wave-uniform base + lane*16.
  __builtin_amdgcn_global_load_lds(
      (const __attribute__((address_space(1))) void*)g,
      (__attribute__((address_space(3))) void*)l, 16, 0, 0);
}

// ---------- prep: dt mean, A_bar = expm(A*mdt) via Taylor, A64 = A_bar^64 ----------
// Wave-cooperative: lane c=tid&63 owns column c (RHS column cached in regs,
// stride-64 reads are 2-way conflicts = free); rows read as wave-uniform
// float4 broadcasts. 11 matmuls of 64x64x64, one 1024-thread block.
__global__ __launch_bounds__(1024) void prep_kernel(
    const float* __restrict__ A, const float* __restrict__ logdt,
    float* __restrict__ Abar, float* __restrict__ A64) {
  const int tid = threadIdx.x;
  const int c = tid & 63;
  const int w = tid >> 6;            // wave id 0..15; rows w, w+16, w+32, w+48
  __shared__ float red[16];
  float e = expf(logdt[tid]);
#pragma unroll
  for (int off = 32; off > 0; off >>= 1) e += __shfl_down(e, off);
  if (c == 0) red[w] = e;
  __syncthreads();
  if (tid == 0) {
    float s = 0.f;
    for (int i = 0; i < 16; i++) s += red[i];
    red[0] = s * (1.f / 1024.f);
  }
  __syncthreads();
  const float mdt = red[0];

  __shared__ float Ms[4096], T[4096], P[4096];
  {
    float m0 = A[tid] * mdt, m1 = A[tid + 1024] * mdt,
          m2 = A[tid + 2048] * mdt, m3 = A[tid + 3072] * mdt;
    Ms[tid] = m0; Ms[tid + 1024] = m1; Ms[tid + 2048] = m2; Ms[tid + 3072] = m3;
    T[tid] = m0; T[tid + 1024] = m1; T[tid + 2048] = m2; T[tid + 3072] = m3;
    P[tid] = m0 + ((tid >> 6) == (tid & 63) ? 1.f : 0.f);
    P[tid + 1024] = m1 + (((tid + 1024) >> 6) == ((tid + 1024) & 63) ? 1.f : 0.f);
    P[tid + 2048] = m2 + (((tid + 2048) >> 6) == ((tid + 2048) & 63) ? 1.f : 0.f);
    P[tid + 3072] = m3 + (((tid + 3072) >> 6) == ((tid + 3072) & 63) ? 1.f : 0.f);
  }
  __syncthreads();
  // cache column c of Ms (constant across Taylor iterations)
  float colM[64];
#pragma unroll
  for (int j = 0; j < 64; j++) colM[j] = Ms[j * 64 + c];
  // Taylor k=2..6 (||Ms|| ~ 3e-3: k=6 term ~1e-15, far below fp32 eps)
  for (int k = 2; k <= 6; k++) {
    const float inv = 1.f / (float)k;
    float accs[4];
#pragma unroll
    for (int i = 0; i < 4; i++) {
      const int r = w + 16 * i;
      const float4* Trow = (const float4*)(T + r * 64);
      float a0 = 0.f, a1 = 0.f, a2 = 0.f, a3 = 0.f;
#pragma unroll
      for (int j4 = 0; j4 < 16; j4++) {
        const float4 t = Trow[j4];               // wave-uniform broadcast
        a0 += t.x * colM[4 * j4 + 0]; a1 += t.y * colM[4 * j4 + 1];
        a2 += t.z * colM[4 * j4 + 2]; a3 += t.w * colM[4 * j4 + 3];
      }
      accs[i] = ((a0 + a1) + (a2 + a3)) * inv;
    }
    __syncthreads();
#pragma unroll
    for (int i = 0; i < 4; i++) {
      const int r = w + 16 * i;
      T[r * 64 + c] = accs[i];
      P[r * 64 + c] += accs[i];
    }
    __syncthreads();
  }
#pragma unroll
  for (int i = 0; i < 4; i++) {
    const int r = w + 16 * i;
    Abar[r * 64 + c] = P[r * 64 + c];
    T[r * 64 + c] = P[r * 64 + c];
  }
  __syncthreads();
  // A64 = Abar^(2^6) via 6 squarings
  for (int sq = 0; sq < 6; sq++) {
    float colT[64];
#pragma unroll
    for (int j = 0; j < 64; j++) colT[j] = T[j * 64 + c];
    float accs[4];
#pragma unroll
    for (int i = 0; i < 4; i++) {
      const int r = w + 16 * i;
      const float4* Trow = (const float4*)(T + r * 64);
      float a0 = 0.f, a1 = 0.f, a2 = 0.f, a3 = 0.f;
#pragma unroll
      for (int j4 = 0; j4 < 16; j4++) {
        const float4 t = Trow[j4];
        a0 += t.x * colT[4 * j4 + 0]; a1 += t.y * colT[4 * j4 + 1];
        a2 += t.z * colT[4 * j4 + 2]; a3 += t.w * colT[4 * j4 + 3];
      }
      accs[i] = (a0 + a1) + (a2 + a3);
    }
    __syncthreads();
#pragma unroll
    for (int i = 0; i < 4; i++) T[(w + 16 * i) * 64 + c] = accs[i];
    __syncthreads();
  }
#pragma unroll
  for (int i = 0; i < 4; i++) {
    const int r = w + 16 * i;
    A64[r * 64 + c] = T[r * 64 + c];
  }
}

// ---------- fp32 -> bf16 weight conversions + B_bar = B * dt ----------
__global__ __launch_bounds__(256) void convert_all(
    const float* __restrict__ wg, const float* __restrict__ wu, const float* __restrict__ wd,
    const float* __restrict__ B, const float* __restrict__ C, const float* __restrict__ logdt,
    unsigned short* __restrict__ wgb, unsigned short* __restrict__ wub,
    unsigned short* __restrict__ wdb, unsigned short* __restrict__ Bb,
    unsigned short* __restrict__ Cb) {
  const size_t NW = (size_t)4096 * 1024;
  const size_t NB = (size_t)64 * 1024;
  const size_t NC = (size_t)1024 * 64;
  const size_t total = 3 * NW + NB + NC;
  for (size_t id = (size_t)blockIdx.x * blockDim.x + threadIdx.x; id < total;
       id += (size_t)gridDim.x * blockDim.x) {
    if (id < NW)            wgb[id] = f2b(wg[id]);
    else if (id < 2 * NW)   wub[id - NW] = f2b(wu[id - NW]);
    else if (id < 3 * NW)   wdb[id - 2 * NW] = f2b(wd[id - 2 * NW]);
    else if (id < 3 * NW + NB) {
      size_t e = id - 3 * NW; int k = (int)(e & 1023);
      Bb[e] = f2b(B[e] * expf(logdt[k]));
    } else {
      size_t e = id - 3 * NW - NB;
      Cb[e] = f2b(C[e]);
    }
  }
}

// ---------- RMSNorm (row = 1024) -> bf16 ----------
__global__ __launch_bounds__(256) void rmsnorm_bf16(
    const float* __restrict__ x, const float* __restrict__ w,
    unsigned short* __restrict__ out) {
  const size_t row = blockIdx.x;
  const int tid = threadIdx.x;
  const float4 v = ((const float4*)(x + row * 1024))[tid];
  float ss = v.x * v.x + v.y * v.y + v.z * v.z + v.w * v.w;
#pragma unroll
  for (int off = 32; off > 0; off >>= 1) ss += __shfl_down(ss, off);
  __shared__ float wsum[4];
  if ((tid & 63) == 0) wsum[tid >> 6] = ss;
  __syncthreads();
  const float tot = wsum[0] + wsum[1] + wsum[2] + wsum[3];
  const float rs = rsqrtf(tot * (1.f / 1024.f) + 1e-6f);
  const float4 wv = ((const float4*)w)[tid];
  ushort4 o;
  o.x = f2b(v.x * rs * wv.x); o.y = f2b(v.y * rs * wv.y);
  o.z = f2b(v.z * rs * wv.z); o.w = f2b(v.w * rs * wv.w);
  ((ushort4*)(out + row * 1024))[tid] = o;
}

// ---------- chunked scan: s_t = Abar s_{t-1} + u_t ----------
// STORE_S==0: zero-init, write chunk-end state. STORE_S==1: carry-init, write all states (bf16).
template <int STORE_S>
__global__ __launch_bounds__(64) void scan_chunk(
    const float* __restrict__ U, const float* __restrict__ Abar,
    const float* __restrict__ carry, float* __restrict__ zend,
    unsigned short* __restrict__ S) {
  const int b = blockIdx.y, c = blockIdx.x;
  const int i = threadIdx.x;
  float a[64];
#pragma unroll
  for (int j = 0; j < 64; j++) a[j] = Abar[i * 64 + j];
  __shared__ float s[64];
  s[i] = STORE_S ? carry[(b * 32 + c) * 64 + i] : 0.f;
  __syncthreads();
  const float* Ub = U + ((size_t)(b * 2048 + c * 64)) * 64;
  for (int t = 0; t < 64; t++) {
    const float u = Ub[t * 64 + i];
    const float4* s4 = (const float4*)s;
    float a0 = u, a1 = 0.f, a2 = 0.f, a3 = 0.f;
#pragma unroll
    for (int j = 0; j < 16; j++) {
      float4 v = s4[j];
      a0 += a[4 * j + 0] * v.x; a1 += a[4 * j + 1] * v.y;
      a2 += a[4 * j + 2] * v.z; a3 += a[4 * j + 3] * v.w;
    }
    const float sn = (a0 + a1) + (a2 + a3);
    __syncthreads();
    s[i] = sn;
    __syncthreads();
    if (STORE_S) S[((size_t)(b * 2048 + c * 64 + t)) * 64 + i] = f2b(sn);
  }
  if (!STORE_S) zend[(b * 32 + c) * 64 + i] = s[i];
}

// carry_c = end-state before chunk c:  e_{-1}=0; carry_c = e_{c-1}; e_c = A64 e_{c-1} + zend_c
__global__ __launch_bounds__(64) void scan_carry(
    const float* __restrict__ zend, const float* __restrict__ A64,
    float* __restrict__ carry) {
  const int b = blockIdx.x;
  const int i = threadIdx.x;
  float a[64];
#pragma unroll
  for (int j = 0; j < 64; j++) a[j] = A64[i * 64 + j];
  __shared__ float s[64];
  s[i] = 0.f;
  __syncthreads();
  for (int c = 0; c < 32; c++) {
    carry[(b * 32 + c) * 64 + i] = s[i];
    const float z = zend[(b * 32 + c) * 64 + i];
    const float4* s4 = (const float4*)s;
    float a0 = z, a1 = 0.f, a2 = 0.f, a3 = 0.f;
#pragma unroll
    for (int j = 0; j < 16; j++) {
      float4 v = s4[j];
      a0 += a[4 * j + 0] * v.x; a1 += a[4 * j + 1] * v.y;
      a2 += a[4 * j + 2] * v.z; a3 += a[4 * j + 3] * v.w;
    }
    const float sn = (a0 + a1) + (a2 + a3);
    __syncthreads();
    s[i] = sn;
    __syncthreads();
  }
}

// ---------- bf16 MFMA GEMM:  C(M,N) = X(M,K) @ W(N,K)^T, fused epilogues ----------
// EPI: 0 = fp32 store | 1 = bf16 store | 2 = silu(e_b)*acc -> bf16 | 3 = e_f + acc -> fp32
//      4 = acc + e_d[n]*bf(e_b) + e_f -> fp32   (SSM out + D*xn + residual)
template <int BM, int BN, int WAVES_M, int WAVES_N, int EPI>
__global__ void __launch_bounds__(256) gemm_bt(
    const unsigned short* __restrict__ X, const unsigned short* __restrict__ W,
    int M, int N, int K,
    float* __restrict__ outf, unsigned short* __restrict__ outb,
    const unsigned short* __restrict__ e_b, const float* __restrict__ e_f,
    const float* __restrict__ e_d) {
  constexpr int BK = 64;                       // 8 chunks of 16B per row
  constexpr int SM = BM / WAVES_M, SN = BN / WAVES_N;
  constexpr int TM = SM / 16, TN = SN / 16;
  __shared__ unsigned short aT[BM * BK];
  __shared__ unsigned short bT[BN * BK];
  const int tid = threadIdx.x;
  const int lane = tid & 63, wave = tid >> 6;
  const int wm = wave / WAVES_N, wn = wave % WAVES_N;
  const int lm = lane & 15, quad = lane >> 4;
  const long bm0 = (long)blockIdx.y * BM;
  const long bn0 = (long)blockIdx.x * BN;
  const int wb = tid & ~63;                    // wave-uniform slot base

  f32x4 acc[TM][TN];
#pragma unroll
  for (int i = 0; i < TM; i++)
#pragma unroll
    for (int j = 0; j < TN; j++) acc[i][j] = (f32x4){0.f, 0.f, 0.f, 0.f};

  for (int k0 = 0; k0 < K; k0 += BK) {
    // stage A,B tiles; LDS layout XOR-swizzled: slot(r,c') holds global chunk c = c'^(r&7)
#pragma unroll
    for (int it = 0; it < (BM * 8) / 256; ++it) {
      int slot = it * 256 + tid;
      int r = slot >> 3, cp = slot & 7, c = cp ^ (r & 7);
      async_ld16(X + (bm0 + r) * (long)K + k0 + c * 8, aT + (it * 256 + wb) * 8);
    }
#pragma unroll
    for (int it = 0; it < (BN * 8) / 256; ++it) {
      int slot = it * 256 + tid;
      int r = slot >> 3, cp = slot & 7, c = cp ^ (r & 7);
      async_ld16(W + (bn0 + r) * (long)K + k0 + c * 8, bT + (it * 256 + wb) * 8);
    }
    __syncthreads();
#pragma unroll
    for (int kk = 0; kk < BK; kk += 32) {
      const int cch = (kk >> 3) + quad;        // 16B chunk holding this lane's 8 k-values
      short8 af[TM], bf[TN];
#pragma unroll
      for (int i = 0; i < TM; i++) {
        int r = wm * SM + i * 16 + lm;
        af[i] = *(const short8*)(aT + (r * 8 + (cch ^ (r & 7))) * 8);
      }
#pragma unroll
      for (int j = 0; j < TN; j++) {
        int r = wn * SN + j * 16 + lm;
        bf[j] = *(const short8*)(bT + (r * 8 + (cch ^ (r & 7))) * 8);
      }
#pragma unroll
      for (int i = 0; i < TM; i++)
#pragma unroll
        for (int j = 0; j < TN; j++)
          acc[i][j] = __builtin_amdgcn_mfma_f32_16x16x32_bf16(af[i], bf[j], acc[i][j], 0, 0, 0);
    }
    __syncthreads();
  }
  // epilogue: C/D layout row = quad*4 + reg, col = lane&15
#pragma unroll
  for (int i = 0; i < TM; i++) {
#pragma unroll
    for (int j = 0; j < TN; j++) {
#pragma unroll
      for (int r = 0; r < 4; r++) {
        const long m = bm0 + wm * SM + i * 16 + quad * 4 + r;
        const long n = bn0 + wn * SN + j * 16 + lm;
        const long idx = m * N + n;
        const float v = acc[i][j][r];
        if (EPI == 0) {
          outf[idx] = v;
        } else if (EPI == 1) {
          outb[idx] = f2b(v);
        } else if (EPI == 2) {
          float g = b2f(e_b[idx]);
          float s = g / (1.f + __expf(-g));
          outb[idx] = f2b(s * v);
        } else if (EPI == 3) {
          outf[idx] = e_f[idx] + v;
        } else if (EPI == 4) {
          outf[idx] = v + e_d[n] * b2f(e_b[idx]) + e_f[idx];
        }
      }
    }
  }
}

// ---------- launch ----------
extern "C" void kernel_launch(void* const* d_in, const int* in_sizes, int n_in,
                              void* d_out, int out_size, void* d_ws, size_t ws_size,
                              hipStream_t stream) {
  const float* x     = (const float*)d_in[0];   // (4,2048,1024)
  const float* A     = (const float*)d_in[1];   // (64,64)
  const float* B     = (const float*)d_in[2];   // (64,1024)
  const float* C     = (const float*)d_in[3];   // (1024,64)
  const float* D     = (const float*)d_in[4];   // (1024,)
  const float* logdt = (const float*)d_in[5];   // (1024,)
  const float* wg    = (const float*)d_in[6];   // (4096,1024)
  const float* wu    = (const float*)d_in[7];   // (4096,1024)
  const float* wd    = (const float*)d_in[8];   // (1024,4096)
  const float* ln1   = (const float*)d_in[9];
  const float* ln2   = (const float*)d_in[10];
  float* out = (float*)d_out;

  char* p = (char*)d_ws;
  auto alloc = [&](size_t bytes) { char* q = p; p += (bytes + 255) & ~(size_t)255; return q; };
  float* Abar  = (float*)alloc(64 * 64 * 4);
  float* A64   = (float*)alloc(64 * 64 * 4);
  float* zend  = (float*)alloc(4 * 32 * 64 * 4);
  float* carry = (float*)alloc(4 * 32 * 64 * 4);
  float* U     = (float*)alloc((size_t)8192 * 64 * 4);
  unsigned short* S    = (unsigned short*)alloc((size_t)8192 * 64 * 2);
  unsigned short* Bb   = (unsigned short*)alloc((size_t)64 * 1024 * 2);
  unsigned short* Cb   = (unsigned short*)alloc((size_t)1024 * 64 * 2);
  unsigned short* wgb  = (unsigned short*)alloc((size_t)4096 * 1024 * 2);
  unsigned short* wub  = (unsigned short*)alloc((size_t)4096 * 1024 * 2);
  unsigned short* wdb  = (unsigned short*)alloc((size_t)1024 * 4096 * 2);
  unsigned short* xnb  = (unsigned short*)alloc((size_t)8192 * 1024 * 2);
  unsigned short* hnb  = (unsigned short*)alloc((size_t)8192 * 1024 * 2);
  float* h             = (float*)alloc((size_t)8192 * 1024 * 4);
  unsigned short* gateb = (unsigned short*)alloc((size_t)8192 * 4096 * 2);
  unsigned short* actb  = (unsigned short*)alloc((size_t)8192 * 4096 * 2);

  prep_kernel<<<1, 1024, 0, stream>>>(A, logdt, Abar, A64);
  convert_all<<<4096, 256, 0, stream>>>(wg, wu, wd, B, C, logdt, wgb, wub, wdb, Bb, Cb);
  rmsnorm_bf16<<<8192, 256, 0, stream>>>(x, ln1, xnb);
  // U = xn @ B_bar^T   (8192x64) — 64x64 tiles -> 128 blocks
  gemm_bt<64, 64, 2, 2, 0><<<dim3(1, 128), 256, 0, stream>>>(
      xnb, Bb, 8192, 64, 1024, U, nullptr, nullptr, nullptr, nullptr);
  // chunked linear scan
  scan_chunk<0><<<dim3(32, 4), 64, 0, stream>>>(U, Abar, carry, zend, S);
  scan_carry<<<4, 64, 0, stream>>>(zend, A64, carry);
  scan_chunk<1><<<dim3(32, 4), 64, 0, stream>>>(U, Abar, carry, zend, S);
  // h = S @ C^T + D*xn + x
  gemm_bt<128, 128, 2, 2, 4><<<dim3(8, 64), 256, 0, stream>>>(
      S, Cb, 8192, 1024, 64, h, nullptr, xnb, x, D);
  rmsnorm_bf16<<<8192, 256, 0, stream>>>(h, ln2, hnb);
  // gate = hn @ wg^T (bf16), act = silu(gate) * (hn @ wu^T) (bf16)
  gemm_bt<128, 128, 2, 2, 1><<<dim3(32, 64), 256, 0, stream>>>(
      hnb, wgb, 8192, 4096, 1024, nullptr, gateb, nullptr, nullptr, nullptr);
  gemm_bt<128, 128, 2, 2, 2><<<dim3(32, 64), 256, 0, stream>>>(
      hnb, wub, 8192, 4096, 1024, nullptr, actb, gateb, nullptr, nullptr);
  // out = h + act @ wd^T
  gemm_bt<128, 128, 2, 2, 3><<<dim3(8, 64), 256, 0, stream>>>(
      actb, wdb, 8192, 1024, 4096, out, nullptr, nullptr, h, nullptr);
}

// Round 3
// 588.060 us; speedup vs baseline: 1.3471x; 1.0594x over previous
//
#include <hip/hip_runtime.h>
#include <hip/hip_bf16.h>
#include <math.h>

// ---------- helpers ----------
typedef __attribute__((ext_vector_type(8))) short short8;   // 8 bf16 = 4 VGPR (MFMA A/B frag)
typedef __attribute__((ext_vector_type(4))) float f32x4;    // MFMA C/D frag

__device__ __forceinline__ unsigned short f2b(float x) {    // fp32 -> bf16 bits, RNE
  union { float f; unsigned int u; } v; v.f = x;
  unsigned int r = v.u + 0x7fffu + ((v.u >> 16) & 1u);
  return (unsigned short)(r >> 16);
}
__device__ __forceinline__ float b2f(unsigned short u) {
  union { unsigned int u; float f; } v; v.u = ((unsigned int)u) << 16;
  return v.f;
}
__device__ __forceinline__ void async_ld16(const void* g, void* l) {
  // global -> LDS direct copy, 16B/lane. LDS dst is wave-uniform base + lane*16.
  __builtin_amdgcn_global_load_lds(
      (const __attribute__((address_space(1))) void*)g,
      (__attribute__((address_space(3))) void*)l, 16, 0, 0);
}

// ---------- prep: dt mean, A_bar = expm(A*mdt) via Taylor, A64 = A_bar^64 ----------
__global__ __launch_bounds__(1024) void prep_kernel(
    const float* __restrict__ A, const float* __restrict__ logdt,
    float* __restrict__ Abar, float* __restrict__ A64) {
  const int tid = threadIdx.x;
  const int c = tid & 63;
  const int w = tid >> 6;            // wave id 0..15; rows w, w+16, w+32, w+48
  __shared__ float red[16];
  float e = expf(logdt[tid]);
#pragma unroll
  for (int off = 32; off > 0; off >>= 1) e += __shfl_down(e, off);
  if (c == 0) red[w] = e;
  __syncthreads();
  if (tid == 0) {
    float s = 0.f;
    for (int i = 0; i < 16; i++) s += red[i];
    red[0] = s * (1.f / 1024.f);
  }
  __syncthreads();
  const float mdt = red[0];

  __shared__ float Ms[4096], T[4096], P[4096];
  {
    float m0 = A[tid] * mdt, m1 = A[tid + 1024] * mdt,
          m2 = A[tid + 2048] * mdt, m3 = A[tid + 3072] * mdt;
    Ms[tid] = m0; Ms[tid + 1024] = m1; Ms[tid + 2048] = m2; Ms[tid + 3072] = m3;
    T[tid] = m0; T[tid + 1024] = m1; T[tid + 2048] = m2; T[tid + 3072] = m3;
    P[tid] = m0 + ((tid >> 6) == (tid & 63) ? 1.f : 0.f);
    P[tid + 1024] = m1 + (((tid + 1024) >> 6) == ((tid + 1024) & 63) ? 1.f : 0.f);
    P[tid + 2048] = m2 + (((tid + 2048) >> 6) == ((tid + 2048) & 63) ? 1.f : 0.f);
    P[tid + 3072] = m3 + (((tid + 3072) >> 6) == ((tid + 3072) & 63) ? 1.f : 0.f);
  }
  __syncthreads();
  float colM[64];
#pragma unroll
  for (int j = 0; j < 64; j++) colM[j] = Ms[j * 64 + c];
  for (int k = 2; k <= 6; k++) {
    const float inv = 1.f / (float)k;
    float accs[4];
#pragma unroll
    for (int i = 0; i < 4; i++) {
      const int r = w + 16 * i;
      const float4* Trow = (const float4*)(T + r * 64);
      float a0 = 0.f, a1 = 0.f, a2 = 0.f, a3 = 0.f;
#pragma unroll
      for (int j4 = 0; j4 < 16; j4++) {
        const float4 t = Trow[j4];               // wave-uniform broadcast
        a0 += t.x * colM[4 * j4 + 0]; a1 += t.y * colM[4 * j4 + 1];
        a2 += t.z * colM[4 * j4 + 2]; a3 += t.w * colM[4 * j4 + 3];
      }
      accs[i] = ((a0 + a1) + (a2 + a3)) * inv;
    }
    __syncthreads();
#pragma unroll
    for (int i = 0; i < 4; i++) {
      const int r = w + 16 * i;
      T[r * 64 + c] = accs[i];
      P[r * 64 + c] += accs[i];
    }
    __syncthreads();
  }
#pragma unroll
  for (int i = 0; i < 4; i++) {
    const int r = w + 16 * i;
    Abar[r * 64 + c] = P[r * 64 + c];
    T[r * 64 + c] = P[r * 64 + c];
  }
  __syncthreads();
  for (int sq = 0; sq < 6; sq++) {
    float colT[64];
#pragma unroll
    for (int j = 0; j < 64; j++) colT[j] = T[j * 64 + c];
    float accs[4];
#pragma unroll
    for (int i = 0; i < 4; i++) {
      const int r = w + 16 * i;
      const float4* Trow = (const float4*)(T + r * 64);
      float a0 = 0.f, a1 = 0.f, a2 = 0.f, a3 = 0.f;
#pragma unroll
      for (int j4 = 0; j4 < 16; j4++) {
        const float4 t = Trow[j4];
        a0 += t.x * colT[4 * j4 + 0]; a1 += t.y * colT[4 * j4 + 1];
        a2 += t.z * colT[4 * j4 + 2]; a3 += t.w * colT[4 * j4 + 3];
      }
      accs[i] = (a0 + a1) + (a2 + a3);
    }
    __syncthreads();
#pragma unroll
    for (int i = 0; i < 4; i++) T[(w + 16 * i) * 64 + c] = accs[i];
    __syncthreads();
  }
#pragma unroll
  for (int i = 0; i < 4; i++) {
    const int r = w + 16 * i;
    A64[r * 64 + c] = T[r * 64 + c];
  }
}

// ---------- fp32 -> bf16 weight conversions + B_bar = B * dt ----------
__global__ __launch_bounds__(256) void convert_all(
    const float* __restrict__ wg, const float* __restrict__ wu, const float* __restrict__ wd,
    const float* __restrict__ B, const float* __restrict__ C, const float* __restrict__ logdt,
    unsigned short* __restrict__ wgb, unsigned short* __restrict__ wub,
    unsigned short* __restrict__ wdb, unsigned short* __restrict__ Bb,
    unsigned short* __restrict__ Cb) {
  const size_t NW = (size_t)4096 * 1024;
  const size_t NB = (size_t)64 * 1024;
  const size_t NC = (size_t)1024 * 64;
  const size_t total = 3 * NW + NB + NC;
  for (size_t id = (size_t)blockIdx.x * blockDim.x + threadIdx.x; id < total;
       id += (size_t)gridDim.x * blockDim.x) {
    if (id < NW)            wgb[id] = f2b(wg[id]);
    else if (id < 2 * NW)   wub[id - NW] = f2b(wu[id - NW]);
    else if (id < 3 * NW)   wdb[id - 2 * NW] = f2b(wd[id - 2 * NW]);
    else if (id < 3 * NW + NB) {
      size_t e = id - 3 * NW; int k = (int)(e & 1023);
      Bb[e] = f2b(B[e] * expf(logdt[k]));
    } else {
      size_t e = id - 3 * NW - NB;
      Cb[e] = f2b(C[e]);
    }
  }
}

// ---------- RMSNorm (row = 1024) -> bf16 ----------
__global__ __launch_bounds__(256) void rmsnorm_bf16(
    const float* __restrict__ x, const float* __restrict__ w,
    unsigned short* __restrict__ out) {
  const size_t row = blockIdx.x;
  const int tid = threadIdx.x;
  const float4 v = ((const float4*)(x + row * 1024))[tid];
  float ss = v.x * v.x + v.y * v.y + v.z * v.z + v.w * v.w;
#pragma unroll
  for (int off = 32; off > 0; off >>= 1) ss += __shfl_down(ss, off);
  __shared__ float wsum[4];
  if ((tid & 63) == 0) wsum[tid >> 6] = ss;
  __syncthreads();
  const float tot = wsum[0] + wsum[1] + wsum[2] + wsum[3];
  const float rs = rsqrtf(tot * (1.f / 1024.f) + 1e-6f);
  const float4 wv = ((const float4*)w)[tid];
  ushort4 o;
  o.x = f2b(v.x * rs * wv.x); o.y = f2b(v.y * rs * wv.y);
  o.z = f2b(v.z * rs * wv.z); o.w = f2b(v.w * rs * wv.w);
  ((ushort4*)(out + row * 1024))[tid] = o;
}

// ---------- chunked scan: s_t = Abar s_{t-1} + u_t ----------
template <int STORE_S>
__global__ __launch_bounds__(64) void scan_chunk(
    const float* __restrict__ U, const float* __restrict__ Abar,
    const float* __restrict__ carry, float* __restrict__ zend,
    unsigned short* __restrict__ S) {
  const int b = blockIdx.y, c = blockIdx.x;
  const int i = threadIdx.x;
  float a[64];
#pragma unroll
  for (int j = 0; j < 64; j++) a[j] = Abar[i * 64 + j];
  __shared__ float s[64];
  s[i] = STORE_S ? carry[(b * 32 + c) * 64 + i] : 0.f;
  __syncthreads();
  const float* Ub = U + ((size_t)(b * 2048 + c * 64)) * 64;
  for (int t = 0; t < 64; t++) {
    const float u = Ub[t * 64 + i];
    const float4* s4 = (const float4*)s;
    float a0 = u, a1 = 0.f, a2 = 0.f, a3 = 0.f;
#pragma unroll
    for (int j = 0; j < 16; j++) {
      float4 v = s4[j];
      a0 += a[4 * j + 0] * v.x; a1 += a[4 * j + 1] * v.y;
      a2 += a[4 * j + 2] * v.z; a3 += a[4 * j + 3] * v.w;
    }
    const float sn = (a0 + a1) + (a2 + a3);
    __syncthreads();
    s[i] = sn;
    __syncthreads();
    if (STORE_S) S[((size_t)(b * 2048 + c * 64 + t)) * 64 + i] = f2b(sn);
  }
  if (!STORE_S) zend[(b * 32 + c) * 64 + i] = s[i];
}

__global__ __launch_bounds__(64) void scan_carry(
    const float* __restrict__ zend, const float* __restrict__ A64,
    float* __restrict__ carry) {
  const int b = blockIdx.x;
  const int i = threadIdx.x;
  float a[64];
#pragma unroll
  for (int j = 0; j < 64; j++) a[j] = A64[i * 64 + j];
  __shared__ float s[64];
  s[i] = 0.f;
  __syncthreads();
  for (int c = 0; c < 32; c++) {
    carry[(b * 32 + c) * 64 + i] = s[i];
    const float z = zend[(b * 32 + c) * 64 + i];
    const float4* s4 = (const float4*)s;
    float a0 = z, a1 = 0.f, a2 = 0.f, a3 = 0.f;
#pragma unroll
    for (int j = 0; j < 16; j++) {
      float4 v = s4[j];
      a0 += a[4 * j + 0] * v.x; a1 += a[4 * j + 1] * v.y;
      a2 += a[4 * j + 2] * v.z; a3 += a[4 * j + 3] * v.w;
    }
    const float sn = (a0 + a1) + (a2 + a3);
    __syncthreads();
    s[i] = sn;
    __syncthreads();
  }
}

// ---------- bf16 MFMA GEMM:  C(M,N) = X(M,K) @ W(N,K)^T, fused epilogues ----------
// EPI: 0 = fp32 store | 3 = e_f + acc -> fp32
//      4 = acc + e_d[n]*bf(e_b) + e_f -> fp32   (SSM out + D*xn + residual)
template <int BM, int BN, int WAVES_M, int WAVES_N, int EPI>
__global__ void __launch_bounds__(256) gemm_bt(
    const unsigned short* __restrict__ X, const unsigned short* __restrict__ W,
    int M, int N, int K,
    float* __restrict__ outf, unsigned short* __restrict__ outb,
    const unsigned short* __restrict__ e_b, const float* __restrict__ e_f,
    const float* __restrict__ e_d) {
  constexpr int BK = 64;                       // 8 chunks of 16B per row
  constexpr int SM = BM / WAVES_M, SN = BN / WAVES_N;
  constexpr int TM = SM / 16, TN = SN / 16;
  __shared__ unsigned short aT[BM * BK];
  __shared__ unsigned short bT[BN * BK];
  const int tid = threadIdx.x;
  const int lane = tid & 63, wave = tid >> 6;
  const int wm = wave / WAVES_N, wn = wave % WAVES_N;
  const int lm = lane & 15, quad = lane >> 4;
  const long bm0 = (long)blockIdx.y * BM;
  const long bn0 = (long)blockIdx.x * BN;
  const int wb = tid & ~63;                    // wave-uniform slot base

  f32x4 acc[TM][TN];
#pragma unroll
  for (int i = 0; i < TM; i++)
#pragma unroll
    for (int j = 0; j < TN; j++) acc[i][j] = (f32x4){0.f, 0.f, 0.f, 0.f};

  for (int k0 = 0; k0 < K; k0 += BK) {
#pragma unroll
    for (int it = 0; it < (BM * 8) / 256; ++it) {
      int slot = it * 256 + tid;
      int r = slot >> 3, cp = slot & 7, c = cp ^ (r & 7);
      async_ld16(X + (bm0 + r) * (long)K + k0 + c * 8, aT + (it * 256 + wb) * 8);
    }
#pragma unroll
    for (int it = 0; it < (BN * 8) / 256; ++it) {
      int slot = it * 256 + tid;
      int r = slot >> 3, cp = slot & 7, c = cp ^ (r & 7);
      async_ld16(W + (bn0 + r) * (long)K + k0 + c * 8, bT + (it * 256 + wb) * 8);
    }
    __syncthreads();
#pragma unroll
    for (int kk = 0; kk < BK; kk += 32) {
      const int cch = (kk >> 3) + quad;
      short8 af[TM], bf[TN];
#pragma unroll
      for (int i = 0; i < TM; i++) {
        int r = wm * SM + i * 16 + lm;
        af[i] = *(const short8*)(aT + (r * 8 + (cch ^ (r & 7))) * 8);
      }
#pragma unroll
      for (int j = 0; j < TN; j++) {
        int r = wn * SN + j * 16 + lm;
        bf[j] = *(const short8*)(bT + (r * 8 + (cch ^ (r & 7))) * 8);
      }
#pragma unroll
      for (int i = 0; i < TM; i++)
#pragma unroll
        for (int j = 0; j < TN; j++)
          acc[i][j] = __builtin_amdgcn_mfma_f32_16x16x32_bf16(af[i], bf[j], acc[i][j], 0, 0, 0);
    }
    __syncthreads();
  }
#pragma unroll
  for (int i = 0; i < TM; i++) {
#pragma unroll
    for (int j = 0; j < TN; j++) {
#pragma unroll
      for (int r = 0; r < 4; r++) {
        const long m = bm0 + wm * SM + i * 16 + quad * 4 + r;
        const long n = bn0 + wn * SN + j * 16 + lm;
        const long idx = m * N + n;
        const float v = acc[i][j][r];
        if (EPI == 0) {
          outf[idx] = v;
        } else if (EPI == 3) {
          outf[idx] = e_f[idx] + v;
        } else if (EPI == 4) {
          outf[idx] = v + e_d[n] * b2f(e_b[idx]) + e_f[idx];
        }
      }
    }
  }
}

// ---------- fused gate+up GEMM: act = silu(X@Wg^T) * (X@Wu^T) -> bf16 ----------
// BM=128, BN=64, 2x2 waves: SM=64,SN=32, TM=4,TN=2, dual acc = 64 VGPRs.
__global__ void __launch_bounds__(256) gemm_gu(
    const unsigned short* __restrict__ X, const unsigned short* __restrict__ Wg,
    const unsigned short* __restrict__ Wu, int M, int N, int K,
    unsigned short* __restrict__ outb) {
  constexpr int BM = 128, BN = 64, BK = 64;
  constexpr int SM = 64, SN = 32, TM = 4, TN = 2;
  __shared__ unsigned short aT[BM * BK];
  __shared__ unsigned short gT[BN * BK];
  __shared__ unsigned short uT[BN * BK];
  const int tid = threadIdx.x;
  const int lane = tid & 63, wave = tid >> 6;
  const int wm = wave >> 1, wn = wave & 1;
  const int lm = lane & 15, quad = lane >> 4;
  const long bm0 = (long)blockIdx.y * BM;
  const long bn0 = (long)blockIdx.x * BN;
  const int wb = tid & ~63;

  f32x4 accg[TM][TN], accu[TM][TN];
#pragma unroll
  for (int i = 0; i < TM; i++)
#pragma unroll
    for (int j = 0; j < TN; j++) {
      accg[i][j] = (f32x4){0.f, 0.f, 0.f, 0.f};
      accu[i][j] = (f32x4){0.f, 0.f, 0.f, 0.f};
    }

  for (int k0 = 0; k0 < K; k0 += BK) {
#pragma unroll
    for (int it = 0; it < 4; ++it) {           // A tile: 128 rows x 8 chunks
      int slot = it * 256 + tid;
      int r = slot >> 3, cp = slot & 7, c = cp ^ (r & 7);
      async_ld16(X + (bm0 + r) * (long)K + k0 + c * 8, aT + (it * 256 + wb) * 8);
    }
#pragma unroll
    for (int it = 0; it < 2; ++it) {           // Wg tile: 64 rows x 8 chunks
      int slot = it * 256 + tid;
      int r = slot >> 3, cp = slot & 7, c = cp ^ (r & 7);
      async_ld16(Wg + (bn0 + r) * (long)K + k0 + c * 8, gT + (it * 256 + wb) * 8);
    }
#pragma unroll
    for (int it = 0; it < 2; ++it) {           // Wu tile
      int slot = it * 256 + tid;
      int r = slot >> 3, cp = slot & 7, c = cp ^ (r & 7);
      async_ld16(Wu + (bn0 + r) * (long)K + k0 + c * 8, uT + (it * 256 + wb) * 8);
    }
    __syncthreads();
#pragma unroll
    for (int kk = 0; kk < BK; kk += 32) {
      const int cch = (kk >> 3) + quad;
      short8 af[TM], gf[TN], uf[TN];
#pragma unroll
      for (int i = 0; i < TM; i++) {
        int r = wm * SM + i * 16 + lm;
        af[i] = *(const short8*)(aT + (r * 8 + (cch ^ (r & 7))) * 8);
      }
#pragma unroll
      for (int j = 0; j < TN; j++) {
        int r = wn * SN + j * 16 + lm;
        gf[j] = *(const short8*)(gT + (r * 8 + (cch ^ (r & 7))) * 8);
        uf[j] = *(const short8*)(uT + (r * 8 + (cch ^ (r & 7))) * 8);
      }
#pragma unroll
      for (int i = 0; i < TM; i++)
#pragma unroll
        for (int j = 0; j < TN; j++) {
          accg[i][j] = __builtin_amdgcn_mfma_f32_16x16x32_bf16(af[i], gf[j], accg[i][j], 0, 0, 0);
          accu[i][j] = __builtin_amdgcn_mfma_f32_16x16x32_bf16(af[i], uf[j], accu[i][j], 0, 0, 0);
        }
    }
    __syncthreads();
  }
#pragma unroll
  for (int i = 0; i < TM; i++) {
#pragma unroll
    for (int j = 0; j < TN; j++) {
#pragma unroll
      for (int r = 0; r < 4; r++) {
        const long m = bm0 + wm * SM + i * 16 + quad * 4 + r;
        const long n = bn0 + wn * SN + j * 16 + lm;
        const float g = accg[i][j][r];
        const float s = g / (1.f + __expf(-g));
        outb[m * N + n] = f2b(s * accu[i][j][r]);
      }
    }
  }
}

// ---------- launch ----------
extern "C" void kernel_launch(void* const* d_in, const int* in_sizes, int n_in,
                              void* d_out, int out_size, void* d_ws, size_t ws_size,
                              hipStream_t stream) {
  const float* x     = (const float*)d_in[0];   // (4,2048,1024)
  const float* A     = (const float*)d_in[1];   // (64,64)
  const float* B     = (const float*)d_in[2];   // (64,1024)
  const float* C     = (const float*)d_in[3];   // (1024,64)
  const float* D     = (const float*)d_in[4];   // (1024,)
  const float* logdt = (const float*)d_in[5];   // (1024,)
  const float* wg    = (const float*)d_in[6];   // (4096,1024)
  const float* wu    = (const float*)d_in[7];   // (4096,1024)
  const float* wd    = (const float*)d_in[8];   // (1024,4096)
  const float* ln1   = (const float*)d_in[9];
  const float* ln2   = (const float*)d_in[10];
  float* out = (float*)d_out;

  char* p = (char*)d_ws;
  auto alloc = [&](size_t bytes) { char* q = p; p += (bytes + 255) & ~(size_t)255; return q; };
  float* Abar  = (float*)alloc(64 * 64 * 4);
  float* A64   = (float*)alloc(64 * 64 * 4);
  float* zend  = (float*)alloc(4 * 32 * 64 * 4);
  float* carry = (float*)alloc(4 * 32 * 64 * 4);
  float* U     = (float*)alloc((size_t)8192 * 64 * 4);
  unsigned short* S    = (unsigned short*)alloc((size_t)8192 * 64 * 2);
  unsigned short* Bb   = (unsigned short*)alloc((size_t)64 * 1024 * 2);
  unsigned short* Cb   = (unsigned short*)alloc((size_t)1024 * 64 * 2);
  unsigned short* wgb  = (unsigned short*)alloc((size_t)4096 * 1024 * 2);
  unsigned short* wub  = (unsigned short*)alloc((size_t)4096 * 1024 * 2);
  unsigned short* wdb  = (unsigned short*)alloc((size_t)1024 * 4096 * 2);
  unsigned short* xnb  = (unsigned short*)alloc((size_t)8192 * 1024 * 2);
  unsigned short* hnb  = (unsigned short*)alloc((size_t)8192 * 1024 * 2);
  float* h             = (float*)alloc((size_t)8192 * 1024 * 4);
  unsigned short* actb = (unsigned short*)alloc((size_t)8192 * 4096 * 2);

  prep_kernel<<<1, 1024, 0, stream>>>(A, logdt, Abar, A64);
  convert_all<<<4096, 256, 0, stream>>>(wg, wu, wd, B, C, logdt, wgb, wub, wdb, Bb, Cb);
  rmsnorm_bf16<<<8192, 256, 0, stream>>>(x, ln1, xnb);
  // U = xn @ B_bar^T   (8192x64) — 32-row tiles -> 256 blocks
  gemm_bt<32, 64, 2, 2, 0><<<dim3(1, 256), 256, 0, stream>>>(
      xnb, Bb, 8192, 64, 1024, U, nullptr, nullptr, nullptr, nullptr);
  // chunked linear scan
  scan_chunk<0><<<dim3(32, 4), 64, 0, stream>>>(U, Abar, carry, zend, S);
  scan_carry<<<4, 64, 0, stream>>>(zend, A64, carry);
  scan_chunk<1><<<dim3(32, 4), 64, 0, stream>>>(U, Abar, carry, zend, S);
  // h = S @ C^T + D*xn + x
  gemm_bt<128, 128, 2, 2, 4><<<dim3(8, 64), 256, 0, stream>>>(
      S, Cb, 8192, 1024, 64, h, nullptr, xnb, x, D);
  rmsnorm_bf16<<<8192, 256, 0, stream>>>(h, ln2, hnb);
  // act = silu(hn @ wg^T) * (hn @ wu^T)  — fused, bf16 out
  gemm_gu<<<dim3(64, 64), 256, 0, stream>>>(hnb, wgb, wub, 8192, 4096, 1024, actb);
  // out = h + act @ wd^T  — BM=64 for 1024 blocks (4/CU)
  gemm_bt<64, 128, 2, 2, 3><<<dim3(8, 128), 256, 0, stream>>>(
      actb, wdb, 8192, 1024, 4096, out, nullptr, nullptr, h, nullptr);
}

// Round 4
// 544.066 us; speedup vs baseline: 1.4560x; 1.0809x over previous
//
#include <hip/hip_runtime.h>
#include <hip/hip_bf16.h>
#include <math.h>

// ---------- helpers ----------
typedef __attribute__((ext_vector_type(8))) short short8;   // 8 bf16 = 4 VGPR (MFMA A/B frag)
typedef __attribute__((ext_vector_type(4))) float f32x4;    // MFMA C/D frag

__device__ __forceinline__ unsigned short f2b(float x) {    // fp32 -> bf16 bits, RNE
  union { float f; unsigned int u; } v; v.f = x;
  unsigned int r = v.u + 0x7fffu + ((v.u >> 16) & 1u);
  return (unsigned short)(r >> 16);
}
__device__ __forceinline__ float b2f(unsigned short u) {
  union { unsigned int u; float f; } v; v.u = ((unsigned int)u) << 16;
  return v.f;
}
// fp32 -> OCP e4m3fn byte, RNE (manual: no header dependency)
__device__ __forceinline__ unsigned char f2f8(float x) {
  float a = fabsf(x);
  unsigned char s = (x < 0.f) ? 0x80 : 0x00;
  if (a >= 464.f) return s | 0x7E;                 // clamp to +-448
  union { float f; unsigned u; } v; v.f = a;
  int e = (int)(v.u >> 23) - 127;
  if (e < -6) {                                    // subnormal: quantum 2^-9
    int q = (int)rintf(a * 512.f);                 // RNE, q in [0,8]
    if (q >= 8) return s | 0x08;                   // rounds up to 2^-6
    return s | (unsigned char)q;
  }
  unsigned mant = v.u & 0x7FFFFF;
  unsigned keep = mant >> 20;
  unsigned rest = mant & 0xFFFFF;
  if (rest > 0x80000u || (rest == 0x80000u && (keep & 1))) keep++;
  unsigned exp8 = (unsigned)(e + 7);
  if (keep == 8) { keep = 0; exp8++; }
  if (exp8 >= 15 && keep >= 7) return s | 0x7E;    // avoid 0x7F (NaN) / overflow
  return s | (unsigned char)((exp8 << 3) | keep);
}
__device__ __forceinline__ void async_ld16(const void* g, void* l) {
  __builtin_amdgcn_global_load_lds(
      (const __attribute__((address_space(1))) void*)g,
      (__attribute__((address_space(3))) void*)l, 16, 0, 0);
}

// ---------- prep (block 0) + Bb/Cb bf16 conversion (blocks 1..) ----------
__global__ __launch_bounds__(1024) void prep_combo(
    const float* __restrict__ A, const float* __restrict__ logdt,
    float* __restrict__ Abar, float* __restrict__ A64,
    const float* __restrict__ B, const float* __restrict__ Cm,
    unsigned short* __restrict__ Bb, unsigned short* __restrict__ Cb) {
  __shared__ float red[16];
  __shared__ float Ms[4096], T[4096], P[4096];
  if (blockIdx.x != 0) {
    const size_t NB = 65536, NC = 65536;
    size_t base = (size_t)(blockIdx.x - 1) * 1024 + threadIdx.x;
    size_t stride = (size_t)(gridDim.x - 1) * 1024;
    for (size_t id = base; id < NB + NC; id += stride) {
      if (id < NB) { int k = (int)(id & 1023); Bb[id] = f2b(B[id] * expf(logdt[k])); }
      else Cb[id - NB] = f2b(Cm[id - NB]);
    }
    return;
  }
  const int tid = threadIdx.x;
  const int c = tid & 63;
  const int w = tid >> 6;
  float e = expf(logdt[tid]);
#pragma unroll
  for (int off = 32; off > 0; off >>= 1) e += __shfl_down(e, off);
  if (c == 0) red[w] = e;
  __syncthreads();
  if (tid == 0) {
    float s = 0.f;
    for (int i = 0; i < 16; i++) s += red[i];
    red[0] = s * (1.f / 1024.f);
  }
  __syncthreads();
  const float mdt = red[0];
  {
    float m0 = A[tid] * mdt, m1 = A[tid + 1024] * mdt,
          m2 = A[tid + 2048] * mdt, m3 = A[tid + 3072] * mdt;
    Ms[tid] = m0; Ms[tid + 1024] = m1; Ms[tid + 2048] = m2; Ms[tid + 3072] = m3;
    T[tid] = m0; T[tid + 1024] = m1; T[tid + 2048] = m2; T[tid + 3072] = m3;
    P[tid] = m0 + ((tid >> 6) == (tid & 63) ? 1.f : 0.f);
    P[tid + 1024] = m1 + (((tid + 1024) >> 6) == ((tid + 1024) & 63) ? 1.f : 0.f);
    P[tid + 2048] = m2 + (((tid + 2048) >> 6) == ((tid + 2048) & 63) ? 1.f : 0.f);
    P[tid + 3072] = m3 + (((tid + 3072) >> 6) == ((tid + 3072) & 63) ? 1.f : 0.f);
  }
  __syncthreads();
  float colM[64];
#pragma unroll
  for (int j = 0; j < 64; j++) colM[j] = Ms[j * 64 + c];
  for (int k = 2; k <= 6; k++) {
    const float inv = 1.f / (float)k;
    float accs[4];
#pragma unroll
    for (int i = 0; i < 4; i++) {
      const int r = w + 16 * i;
      const float4* Trow = (const float4*)(T + r * 64);
      float a0 = 0.f, a1 = 0.f, a2 = 0.f, a3 = 0.f;
#pragma unroll
      for (int j4 = 0; j4 < 16; j4++) {
        const float4 t = Trow[j4];
        a0 += t.x * colM[4 * j4 + 0]; a1 += t.y * colM[4 * j4 + 1];
        a2 += t.z * colM[4 * j4 + 2]; a3 += t.w * colM[4 * j4 + 3];
      }
      accs[i] = ((a0 + a1) + (a2 + a3)) * inv;
    }
    __syncthreads();
#pragma unroll
    for (int i = 0; i < 4; i++) {
      const int r = w + 16 * i;
      T[r * 64 + c] = accs[i];
      P[r * 64 + c] += accs[i];
    }
    __syncthreads();
  }
#pragma unroll
  for (int i = 0; i < 4; i++) {
    const int r = w + 16 * i;
    Abar[r * 64 + c] = P[r * 64 + c];
    T[r * 64 + c] = P[r * 64 + c];
  }
  __syncthreads();
  for (int sq = 0; sq < 6; sq++) {
    float colT[64];
#pragma unroll
    for (int j = 0; j < 64; j++) colT[j] = T[j * 64 + c];
    float accs[4];
#pragma unroll
    for (int i = 0; i < 4; i++) {
      const int r = w + 16 * i;
      const float4* Trow = (const float4*)(T + r * 64);
      float a0 = 0.f, a1 = 0.f, a2 = 0.f, a3 = 0.f;
#pragma unroll
      for (int j4 = 0; j4 < 16; j4++) {
        const float4 t = Trow[j4];
        a0 += t.x * colT[4 * j4 + 0]; a1 += t.y * colT[4 * j4 + 1];
        a2 += t.z * colT[4 * j4 + 2]; a3 += t.w * colT[4 * j4 + 3];
      }
      accs[i] = (a0 + a1) + (a2 + a3);
    }
    __syncthreads();
#pragma unroll
    for (int i = 0; i < 4; i++) T[(w + 16 * i) * 64 + c] = accs[i];
    __syncthreads();
  }
#pragma unroll
  for (int i = 0; i < 4; i++) {
    const int r = w + 16 * i;
    A64[r * 64 + c] = T[r * 64 + c];
  }
}

// ---------- RMSNorm (row = 1024) -> bf16 ----------
__global__ __launch_bounds__(256) void rmsnorm_bf16(
    const float* __restrict__ x, const float* __restrict__ w,
    unsigned short* __restrict__ out) {
  const size_t row = blockIdx.x;
  const int tid = threadIdx.x;
  const float4 v = ((const float4*)(x + row * 1024))[tid];
  float ss = v.x * v.x + v.y * v.y + v.z * v.z + v.w * v.w;
#pragma unroll
  for (int off = 32; off > 0; off >>= 1) ss += __shfl_down(ss, off);
  __shared__ float wsum[4];
  if ((tid & 63) == 0) wsum[tid >> 6] = ss;
  __syncthreads();
  const float tot = wsum[0] + wsum[1] + wsum[2] + wsum[3];
  const float rs = rsqrtf(tot * (1.f / 1024.f) + 1e-6f);
  const float4 wv = ((const float4*)w)[tid];
  ushort4 o;
  o.x = f2b(v.x * rs * wv.x); o.y = f2b(v.y * rs * wv.y);
  o.z = f2b(v.z * rs * wv.z); o.w = f2b(v.w * rs * wv.w);
  ((ushort4*)(out + row * 1024))[tid] = o;
}

// ---------- scan (32 blocks, 4 chunk-waves each) + weight-convert blocks ----------
// CONV: 1 = fp32->bf16, 2 = fp32*64 -> fp8(e4m3)
template <int STORE_S, int CONV>
__global__ __launch_bounds__(256) void scan_combo(
    const float* __restrict__ U, const float* __restrict__ Abar,
    const float* __restrict__ carry, float* __restrict__ zend,
    unsigned short* __restrict__ S,
    const float* __restrict__ csrc, void* __restrict__ cdst, size_t ccount) {
  constexpr int SCAN_BLOCKS = 32;
  __shared__ float s[4][64];
  if (blockIdx.x >= SCAN_BLOCKS) {
    size_t base = (size_t)(blockIdx.x - SCAN_BLOCKS) * 256 + threadIdx.x;
    size_t stride = (size_t)(gridDim.x - SCAN_BLOCKS) * 256;
    for (size_t id = base; id < ccount; id += stride) {
      if (CONV == 1) ((unsigned short*)cdst)[id] = f2b(csrc[id]);
      else           ((unsigned char*)cdst)[id] = f2f8(csrc[id] * 64.f);
    }
    return;
  }
  const int wave = threadIdx.x >> 6, i = threadIdx.x & 63;
  const int task = blockIdx.x * 4 + wave;          // 128 tasks = 4 batch x 32 chunks
  const int b = task >> 5, c = task & 31;
  float a[64];
#pragma unroll
  for (int j = 0; j < 64; j++) a[j] = Abar[i * 64 + j];
  float cur = STORE_S ? carry[(b * 32 + c) * 64 + i] : 0.f;
  const float* Ub = U + ((size_t)(b * 2048 + c * 64)) * 64;
  for (int t = 0; t < 64; t++) {
    s[wave][i] = cur;
    __syncthreads();
    const float u = Ub[t * 64 + i];
    const float4* s4 = (const float4*)s[wave];
    float a0 = u, a1 = 0.f, a2 = 0.f, a3 = 0.f;
#pragma unroll
    for (int j = 0; j < 16; j++) {
      float4 v = s4[j];
      a0 += a[4 * j + 0] * v.x; a1 += a[4 * j + 1] * v.y;
      a2 += a[4 * j + 2] * v.z; a3 += a[4 * j + 3] * v.w;
    }
    cur = (a0 + a1) + (a2 + a3);
    __syncthreads();
    if (STORE_S) S[((size_t)(b * 2048 + c * 64 + t)) * 64 + i] = f2b(cur);
  }
  if (!STORE_S) zend[(b * 32 + c) * 64 + i] = cur;
}

// ---------- carry recurrence (block 0, 4 batch-waves) + wu convert blocks ----------
__global__ __launch_bounds__(256) void carry_combo(
    const float* __restrict__ zend, const float* __restrict__ A64,
    float* __restrict__ carry,
    const float* __restrict__ csrc, unsigned short* __restrict__ cdst, size_t ccount) {
  __shared__ float s[4][64];
  if (blockIdx.x != 0) {
    size_t base = (size_t)(blockIdx.x - 1) * 256 + threadIdx.x;
    size_t stride = (size_t)(gridDim.x - 1) * 256;
    for (size_t id = base; id < ccount; id += stride) cdst[id] = f2b(csrc[id]);
    return;
  }
  const int b = threadIdx.x >> 6, i = threadIdx.x & 63;
  float a[64];
#pragma unroll
  for (int j = 0; j < 64; j++) a[j] = A64[i * 64 + j];
  float cur = 0.f;
  for (int c = 0; c < 32; c++) {
    carry[(b * 32 + c) * 64 + i] = cur;
    s[b][i] = cur;
    __syncthreads();
    const float z = zend[(b * 32 + c) * 64 + i];
    const float4* s4 = (const float4*)s[b];
    float a0 = z, a1 = 0.f, a2 = 0.f, a3 = 0.f;
#pragma unroll
    for (int j = 0; j < 16; j++) {
      float4 v = s4[j];
      a0 += a[4 * j + 0] * v.x; a1 += a[4 * j + 1] * v.y;
      a2 += a[4 * j + 2] * v.z; a3 += a[4 * j + 3] * v.w;
    }
    cur = (a0 + a1) + (a2 + a3);
    __syncthreads();
  }
}

// ---------- bf16 MFMA GEMM:  C(M,N) = X(M,K) @ W(N,K)^T ----------
// EPI: 0 = fp32 store | 4 = acc + e_d[n]*bf(e_b) + e_f -> fp32
template <int BM, int BN, int WAVES_M, int WAVES_N, int EPI>
__global__ void __launch_bounds__(256) gemm_bt(
    const unsigned short* __restrict__ X, const unsigned short* __restrict__ W,
    int M, int N, int K,
    float* __restrict__ outf, const unsigned short* __restrict__ e_b,
    const float* __restrict__ e_f, const float* __restrict__ e_d) {
  constexpr int BK = 64;
  constexpr int SM = BM / WAVES_M, SN = BN / WAVES_N;
  constexpr int TM = SM / 16, TN = SN / 16;
  __shared__ unsigned short aT[BM * BK];
  __shared__ unsigned short bT[BN * BK];
  const int tid = threadIdx.x;
  const int lane = tid & 63, wave = tid >> 6;
  const int wm = wave / WAVES_N, wn = wave % WAVES_N;
  const int lm = lane & 15, quad = lane >> 4;
  const long bm0 = (long)blockIdx.y * BM;
  const long bn0 = (long)blockIdx.x * BN;
  const int wb = tid & ~63;

  f32x4 acc[TM][TN];
#pragma unroll
  for (int i = 0; i < TM; i++)
#pragma unroll
    for (int j = 0; j < TN; j++) acc[i][j] = (f32x4){0.f, 0.f, 0.f, 0.f};

  for (int k0 = 0; k0 < K; k0 += BK) {
#pragma unroll
    for (int it = 0; it < (BM * 8) / 256; ++it) {
      int slot = it * 256 + tid;
      int r = slot >> 3, cp = slot & 7, c = cp ^ (r & 7);
      async_ld16(X + (bm0 + r) * (long)K + k0 + c * 8, aT + (it * 256 + wb) * 8);
    }
#pragma unroll
    for (int it = 0; it < (BN * 8) / 256; ++it) {
      int slot = it * 256 + tid;
      int r = slot >> 3, cp = slot & 7, c = cp ^ (r & 7);
      async_ld16(W + (bn0 + r) * (long)K + k0 + c * 8, bT + (it * 256 + wb) * 8);
    }
    __syncthreads();
#pragma unroll
    for (int kk = 0; kk < BK; kk += 32) {
      const int cch = (kk >> 3) + quad;
      short8 af[TM], bf[TN];
#pragma unroll
      for (int i = 0; i < TM; i++) {
        int r = wm * SM + i * 16 + lm;
        af[i] = *(const short8*)(aT + (r * 8 + (cch ^ (r & 7))) * 8);
      }
#pragma unroll
      for (int j = 0; j < TN; j++) {
        int r = wn * SN + j * 16 + lm;
        bf[j] = *(const short8*)(bT + (r * 8 + (cch ^ (r & 7))) * 8);
      }
#pragma unroll
      for (int i = 0; i < TM; i++)
#pragma unroll
        for (int j = 0; j < TN; j++)
          acc[i][j] = __builtin_amdgcn_mfma_f32_16x16x32_bf16(af[i], bf[j], acc[i][j], 0, 0, 0);
    }
    __syncthreads();
  }
#pragma unroll
  for (int i = 0; i < TM; i++) {
#pragma unroll
    for (int j = 0; j < TN; j++) {
#pragma unroll
      for (int r = 0; r < 4; r++) {
        const long m = bm0 + wm * SM + i * 16 + quad * 4 + r;
        const long n = bn0 + wn * SN + j * 16 + lm;
        const long idx = m * N + n;
        const float v = acc[i][j][r];
        if (EPI == 0) outf[idx] = v;
        else if (EPI == 4) outf[idx] = v + e_d[n] * b2f(e_b[idx]) + e_f[idx];
      }
    }
  }
}

// ---------- fused gate+up GEMM: act = silu(X@Wg^T)*(X@Wu^T) -> fp8 e4m3 ----------
__global__ void __launch_bounds__(256) gemm_gu(
    const unsigned short* __restrict__ X, const unsigned short* __restrict__ Wg,
    const unsigned short* __restrict__ Wu, int M, int N, int K,
    unsigned char* __restrict__ out8) {
  constexpr int BM = 128, BN = 64, BK = 64;
  constexpr int SM = 64, SN = 32, TM = 4, TN = 2;
  __shared__ unsigned short aT[BM * BK];
  __shared__ unsigned short gT[BN * BK];
  __shared__ unsigned short uT[BN * BK];
  const int tid = threadIdx.x;
  const int lane = tid & 63, wave = tid >> 6;
  const int wm = wave >> 1, wn = wave & 1;
  const int lm = lane & 15, quad = lane >> 4;
  const long bm0 = (long)blockIdx.y * BM;
  const long bn0 = (long)blockIdx.x * BN;
  const int wb = tid & ~63;

  f32x4 accg[TM][TN], accu[TM][TN];
#pragma unroll
  for (int i = 0; i < TM; i++)
#pragma unroll
    for (int j = 0; j < TN; j++) {
      accg[i][j] = (f32x4){0.f, 0.f, 0.f, 0.f};
      accu[i][j] = (f32x4){0.f, 0.f, 0.f, 0.f};
    }

  for (int k0 = 0; k0 < K; k0 += BK) {
#pragma unroll
    for (int it = 0; it < 4; ++it) {
      int slot = it * 256 + tid;
      int r = slot >> 3, cp = slot & 7, c = cp ^ (r & 7);
      async_ld16(X + (bm0 + r) * (long)K + k0 + c * 8, aT + (it * 256 + wb) * 8);
    }
#pragma unroll
    for (int it = 0; it < 2; ++it) {
      int slot = it * 256 + tid;
      int r = slot >> 3, cp = slot & 7, c = cp ^ (r & 7);
      async_ld16(Wg + (bn0 + r) * (long)K + k0 + c * 8, gT + (it * 256 + wb) * 8);
    }
#pragma unroll
    for (int it = 0; it < 2; ++it) {
      int slot = it * 256 + tid;
      int r = slot >> 3, cp = slot & 7, c = cp ^ (r & 7);
      async_ld16(Wu + (bn0 + r) * (long)K + k0 + c * 8, uT + (it * 256 + wb) * 8);
    }
    __syncthreads();
#pragma unroll
    for (int kk = 0; kk < BK; kk += 32) {
      const int cch = (kk >> 3) + quad;
      short8 af[TM], gf[TN], uf[TN];
#pragma unroll
      for (int i = 0; i < TM; i++) {
        int r = wm * SM + i * 16 + lm;
        af[i] = *(const short8*)(aT + (r * 8 + (cch ^ (r & 7))) * 8);
      }
#pragma unroll
      for (int j = 0; j < TN; j++) {
        int r = wn * SN + j * 16 + lm;
        gf[j] = *(const short8*)(gT + (r * 8 + (cch ^ (r & 7))) * 8);
        uf[j] = *(const short8*)(uT + (r * 8 + (cch ^ (r & 7))) * 8);
      }
#pragma unroll
      for (int i = 0; i < TM; i++)
#pragma unroll
        for (int j = 0; j < TN; j++) {
          accg[i][j] = __builtin_amdgcn_mfma_f32_16x16x32_bf16(af[i], gf[j], accg[i][j], 0, 0, 0);
          accu[i][j] = __builtin_amdgcn_mfma_f32_16x16x32_bf16(af[i], uf[j], accu[i][j], 0, 0, 0);
        }
    }
    __syncthreads();
  }
#pragma unroll
  for (int i = 0; i < TM; i++) {
#pragma unroll
    for (int j = 0; j < TN; j++) {
#pragma unroll
      for (int r = 0; r < 4; r++) {
        const long m = bm0 + wm * SM + i * 16 + quad * 4 + r;
        const long n = bn0 + wn * SN + j * 16 + lm;
        const float g = accg[i][j][r];
        const float s = g / (1.f + __expf(-g));
        out8[m * N + n] = f2f8(s * accu[i][j][r]);
      }
    }
  }
}

// ---------- fp8 MFMA GEMM (down proj): out = (X8 @ W8^T)*inv + e_f ----------
// BM=128, BN=64, 2x2 waves. Row = 64 fp8 = 4 chunks of 16B. Swizzle s(r)=(r+(r>>2))&3.
__global__ void __launch_bounds__(256) gemm_f8(
    const unsigned char* __restrict__ X, const unsigned char* __restrict__ W,
    int M, int N, int K,
    float* __restrict__ outf, const float* __restrict__ e_f, float inv) {
  constexpr int BM = 128, BN = 64, BK = 64;
  constexpr int SM = 64, SN = 32, TM = 4, TN = 2;
  __shared__ unsigned char aT[BM * BK];   // 8 KB
  __shared__ unsigned char bT[BN * BK];   // 4 KB
  const int tid = threadIdx.x;
  const int lane = tid & 63, wave = tid >> 6;
  const int wm = wave >> 1, wn = wave & 1;
  const int lm = lane & 15, quad = lane >> 4;
  const long bm0 = (long)blockIdx.y * BM;
  const long bn0 = (long)blockIdx.x * BN;
  const int wb = tid & ~63;

  f32x4 acc[TM][TN];
#pragma unroll
  for (int i = 0; i < TM; i++)
#pragma unroll
    for (int j = 0; j < TN; j++) acc[i][j] = (f32x4){0.f, 0.f, 0.f, 0.f};

  for (int k0 = 0; k0 < K; k0 += BK) {
#pragma unroll
    for (int it = 0; it < 2; ++it) {       // A: 128 rows x 4 chunks = 512 slots
      int slot = it * 256 + tid;
      int r = slot >> 2, cp = slot & 3, c = cp ^ ((r + (r >> 2)) & 3);
      async_ld16(X + (bm0 + r) * (long)K + k0 + c * 16, aT + (it * 256 + wb) * 16);
    }
    {                                      // B: 64 rows x 4 chunks = 256 slots
      int r = tid >> 2, cp = tid & 3, c = cp ^ ((r + (r >> 2)) & 3);
      async_ld16(W + (bn0 + r) * (long)K + k0 + c * 16, bT + wb * 16);
    }
    __syncthreads();
#pragma unroll
    for (int kk = 0; kk < BK; kk += 32) {
      const int cc = (kk >> 4) + (quad >> 1);
      const int half = (quad & 1) * 8;
      long af[TM], bf[TN];
#pragma unroll
      for (int i = 0; i < TM; i++) {
        int r = wm * SM + i * 16 + lm;
        af[i] = *(const long*)(aT + (r * 4 + (cc ^ ((r + (r >> 2)) & 3))) * 16 + half);
      }
#pragma unroll
      for (int j = 0; j < TN; j++) {
        int r = wn * SN + j * 16 + lm;
        bf[j] = *(const long*)(bT + (r * 4 + (cc ^ ((r + (r >> 2)) & 3))) * 16 + half);
      }
#pragma unroll
      for (int i = 0; i < TM; i++)
#pragma unroll
        for (int j = 0; j < TN; j++)
          acc[i][j] = __builtin_amdgcn_mfma_f32_16x16x32_fp8_fp8(af[i], bf[j], acc[i][j], 0, 0, 0);
    }
    __syncthreads();
  }
#pragma unroll
  for (int i = 0; i < TM; i++) {
#pragma unroll
    for (int j = 0; j < TN; j++) {
#pragma unroll
      for (int r = 0; r < 4; r++) {
        const long m = bm0 + wm * SM + i * 16 + quad * 4 + r;
        const long n = bn0 + wn * SN + j * 16 + lm;
        const long idx = m * N + n;
        outf[idx] = acc[i][j][r] * inv + e_f[idx];
      }
    }
  }
}

// ---------- launch ----------
extern "C" void kernel_launch(void* const* d_in, const int* in_sizes, int n_in,
                              void* d_out, int out_size, void* d_ws, size_t ws_size,
                              hipStream_t stream) {
  const float* x     = (const float*)d_in[0];   // (4,2048,1024)
  const float* A     = (const float*)d_in[1];   // (64,64)
  const float* B     = (const float*)d_in[2];   // (64,1024)
  const float* C     = (const float*)d_in[3];   // (1024,64)
  const float* D     = (const float*)d_in[4];   // (1024,)
  const float* logdt = (const float*)d_in[5];   // (1024,)
  const float* wg    = (const float*)d_in[6];   // (4096,1024)
  const float* wu    = (const float*)d_in[7];   // (4096,1024)
  const float* wd    = (const float*)d_in[8];   // (1024,4096)
  const float* ln1   = (const float*)d_in[9];
  const float* ln2   = (const float*)d_in[10];
  float* out = (float*)d_out;

  char* p = (char*)d_ws;
  auto alloc = [&](size_t bytes) { char* q = p; p += (bytes + 255) & ~(size_t)255; return q; };
  float* Abar  = (float*)alloc(64 * 64 * 4);
  float* A64   = (float*)alloc(64 * 64 * 4);
  float* zend  = (float*)alloc(4 * 32 * 64 * 4);
  float* carry = (float*)alloc(4 * 32 * 64 * 4);
  float* U     = (float*)alloc((size_t)8192 * 64 * 4);
  unsigned short* S    = (unsigned short*)alloc((size_t)8192 * 64 * 2);
  unsigned short* Bb   = (unsigned short*)alloc((size_t)64 * 1024 * 2);
  unsigned short* Cb   = (unsigned short*)alloc((size_t)1024 * 64 * 2);
  unsigned short* wgb  = (unsigned short*)alloc((size_t)4096 * 1024 * 2);
  unsigned short* wub  = (unsigned short*)alloc((size_t)4096 * 1024 * 2);
  unsigned char*  wd8  = (unsigned char*)alloc((size_t)1024 * 4096);
  unsigned short* xnb  = (unsigned short*)alloc((size_t)8192 * 1024 * 2);
  unsigned short* hnb  = (unsigned short*)alloc((size_t)8192 * 1024 * 2);
  float* h             = (float*)alloc((size_t)8192 * 1024 * 4);
  unsigned char*  act8 = (unsigned char*)alloc((size_t)8192 * 4096);

  const size_t NWG = (size_t)4096 * 1024;

  prep_combo<<<33, 1024, 0, stream>>>(A, logdt, Abar, A64, B, C, Bb, Cb);
  rmsnorm_bf16<<<8192, 256, 0, stream>>>(x, ln1, xnb);
  // U = xn @ B_bar^T
  gemm_bt<32, 64, 2, 2, 0><<<dim3(1, 256), 256, 0, stream>>>(
      xnb, Bb, 8192, 64, 1024, U, nullptr, nullptr, nullptr);
  // scan pass 1 (zero-init, chunk ends) + wg->bf16 convert
  scan_combo<0, 1><<<32 + 1024, 256, 0, stream>>>(
      U, Abar, nullptr, zend, S, wg, wgb, NWG);
  // carry recurrence + wu->bf16 convert
  carry_combo<<<1 + 1024, 256, 0, stream>>>(zend, A64, carry, wu, wub, NWG);
  // scan pass 2 (carry-init, all states bf16) + wd*64->fp8 convert
  scan_combo<1, 2><<<32 + 1024, 256, 0, stream>>>(
      U, Abar, carry, zend, S, wd, wd8, NWG);
  // h = S @ C^T + D*xn + x
  gemm_bt<128, 128, 2, 2, 4><<<dim3(8, 64), 256, 0, stream>>>(
      S, Cb, 8192, 1024, 64, h, xnb, x, D);
  rmsnorm_bf16<<<8192, 256, 0, stream>>>(h, ln2, hnb);
  // act = silu(hn @ wg^T) * (hn @ wu^T) -> fp8
  gemm_gu<<<dim3(64, 64), 256, 0, stream>>>(hnb, wgb, wub, 8192, 4096, 1024, act8);
  // out = h + (act8 @ wd8^T)/64
  gemm_f8<<<dim3(16, 64), 256, 0, stream>>>(
      act8, wd8, 8192, 1024, 4096, out, h, 1.f / 64.f);
}

// Round 5
// 506.637 us; speedup vs baseline: 1.5636x; 1.0739x over previous
//
#include <hip/hip_runtime.h>
#include <hip/hip_bf16.h>
#include <math.h>

// ---------- helpers ----------
typedef __attribute__((ext_vector_type(8))) short short8;   // 8 bf16 = 4 VGPR (MFMA A/B frag)
typedef __attribute__((ext_vector_type(4))) float f32x4;    // MFMA C/D frag

__device__ __forceinline__ unsigned short f2b(float x) {    // fp32 -> bf16 bits, RNE
  union { float f; unsigned int u; } v; v.f = x;
  unsigned int r = v.u + 0x7fffu + ((v.u >> 16) & 1u);
  return (unsigned short)(r >> 16);
}
__device__ __forceinline__ float b2f(unsigned short u) {
  union { unsigned int u; float f; } v; v.u = ((unsigned int)u) << 16;
  return v.f;
}
// fp32 -> OCP e4m3fn byte (software fallback), RNE
__device__ __forceinline__ unsigned char f2f8_sw(float x) {
  float a = fabsf(x);
  unsigned char s = (x < 0.f) ? 0x80 : 0x00;
  if (a >= 464.f) return s | 0x7E;
  union { float f; unsigned u; } v; v.f = a;
  int e = (int)(v.u >> 23) - 127;
  if (e < -6) {
    int q = (int)rintf(a * 512.f);
    if (q >= 8) return s | 0x08;
    return s | (unsigned char)q;
  }
  unsigned mant = v.u & 0x7FFFFF;
  unsigned keep = mant >> 20;
  unsigned rest = mant & 0xFFFFF;
  if (rest > 0x80000u || (rest == 0x80000u && (keep & 1))) keep++;
  unsigned exp8 = (unsigned)(e + 7);
  if (keep == 8) { keep = 0; exp8++; }
  if (exp8 >= 15 && keep >= 7) return s | 0x7E;
  return s | (unsigned char)((exp8 << 3) | keep);
}
#if __has_builtin(__builtin_amdgcn_cvt_pk_fp8_f32)
__device__ __forceinline__ unsigned char f2f8(float x) {
  return (unsigned char)(__builtin_amdgcn_cvt_pk_fp8_f32(x, x, 0, false) & 0xFF);
}
__device__ __forceinline__ unsigned int f8pack4(float a, float b, float c, float d) {
  int w0 = __builtin_amdgcn_cvt_pk_fp8_f32(a, b, 0, false);
  return (unsigned int)__builtin_amdgcn_cvt_pk_fp8_f32(c, d, w0, true);
}
#else
__device__ __forceinline__ unsigned char f2f8(float x) { return f2f8_sw(x); }
__device__ __forceinline__ unsigned int f8pack4(float a, float b, float c, float d) {
  return (unsigned)f2f8_sw(a) | ((unsigned)f2f8_sw(b) << 8) |
         ((unsigned)f2f8_sw(c) << 16) | ((unsigned)f2f8_sw(d) << 24);
}
#endif
__device__ __forceinline__ void async_ld16(const void* g, void* l) {
  __builtin_amdgcn_global_load_lds(
      (const __attribute__((address_space(1))) void*)g,
      (__attribute__((address_space(3))) void*)l, 16, 0, 0);
}

// ---------- prep (block 0) + Bb/Cb bf16 conversion (blocks 1..) ----------
__global__ __launch_bounds__(1024) void prep_combo(
    const float* __restrict__ A, const float* __restrict__ logdt,
    float* __restrict__ Abar, float* __restrict__ A64,
    const float* __restrict__ B, const float* __restrict__ Cm,
    unsigned short* __restrict__ Bb, unsigned short* __restrict__ Cb) {
  __shared__ float red[16];
  __shared__ float Ms[4096], T[4096], P[4096];
  if (blockIdx.x != 0) {
    const size_t NB = 65536, NC = 65536;
    size_t base = (size_t)(blockIdx.x - 1) * 1024 + threadIdx.x;
    size_t stride = (size_t)(gridDim.x - 1) * 1024;
    for (size_t id = base; id < NB + NC; id += stride) {
      if (id < NB) { int k = (int)(id & 1023); Bb[id] = f2b(B[id] * expf(logdt[k])); }
      else Cb[id - NB] = f2b(Cm[id - NB]);
    }
    return;
  }
  const int tid = threadIdx.x;
  const int c = tid & 63;
  const int w = tid >> 6;
  float e = expf(logdt[tid]);
#pragma unroll
  for (int off = 32; off > 0; off >>= 1) e += __shfl_down(e, off);
  if (c == 0) red[w] = e;
  __syncthreads();
  if (tid == 0) {
    float s = 0.f;
    for (int i = 0; i < 16; i++) s += red[i];
    red[0] = s * (1.f / 1024.f);
  }
  __syncthreads();
  const float mdt = red[0];
  {
    float m0 = A[tid] * mdt, m1 = A[tid + 1024] * mdt,
          m2 = A[tid + 2048] * mdt, m3 = A[tid + 3072] * mdt;
    Ms[tid] = m0; Ms[tid + 1024] = m1; Ms[tid + 2048] = m2; Ms[tid + 3072] = m3;
    T[tid] = m0; T[tid + 1024] = m1; T[tid + 2048] = m2; T[tid + 3072] = m3;
    P[tid] = m0 + ((tid >> 6) == (tid & 63) ? 1.f : 0.f);
    P[tid + 1024] = m1 + (((tid + 1024) >> 6) == ((tid + 1024) & 63) ? 1.f : 0.f);
    P[tid + 2048] = m2 + (((tid + 2048) >> 6) == ((tid + 2048) & 63) ? 1.f : 0.f);
    P[tid + 3072] = m3 + (((tid + 3072) >> 6) == ((tid + 3072) & 63) ? 1.f : 0.f);
  }
  __syncthreads();
  float colM[64];
#pragma unroll
  for (int j = 0; j < 64; j++) colM[j] = Ms[j * 64 + c];
  for (int k = 2; k <= 6; k++) {
    const float inv = 1.f / (float)k;
    float accs[4];
#pragma unroll
    for (int i = 0; i < 4; i++) {
      const int r = w + 16 * i;
      const float4* Trow = (const float4*)(T + r * 64);
      float a0 = 0.f, a1 = 0.f, a2 = 0.f, a3 = 0.f;
#pragma unroll
      for (int j4 = 0; j4 < 16; j4++) {
        const float4 t = Trow[j4];
        a0 += t.x * colM[4 * j4 + 0]; a1 += t.y * colM[4 * j4 + 1];
        a2 += t.z * colM[4 * j4 + 2]; a3 += t.w * colM[4 * j4 + 3];
      }
      accs[i] = ((a0 + a1) + (a2 + a3)) * inv;
    }
    __syncthreads();
#pragma unroll
    for (int i = 0; i < 4; i++) {
      const int r = w + 16 * i;
      T[r * 64 + c] = accs[i];
      P[r * 64 + c] += accs[i];
    }
    __syncthreads();
  }
#pragma unroll
  for (int i = 0; i < 4; i++) {
    const int r = w + 16 * i;
    Abar[r * 64 + c] = P[r * 64 + c];
    T[r * 64 + c] = P[r * 64 + c];
  }
  __syncthreads();
  for (int sq = 0; sq < 6; sq++) {
    float colT[64];
#pragma unroll
    for (int j = 0; j < 64; j++) colT[j] = T[j * 64 + c];
    float accs[4];
#pragma unroll
    for (int i = 0; i < 4; i++) {
      const int r = w + 16 * i;
      const float4* Trow = (const float4*)(T + r * 64);
      float a0 = 0.f, a1 = 0.f, a2 = 0.f, a3 = 0.f;
#pragma unroll
      for (int j4 = 0; j4 < 16; j4++) {
        const float4 t = Trow[j4];
        a0 += t.x * colT[4 * j4 + 0]; a1 += t.y * colT[4 * j4 + 1];
        a2 += t.z * colT[4 * j4 + 2]; a3 += t.w * colT[4 * j4 + 3];
      }
      accs[i] = (a0 + a1) + (a2 + a3);
    }
    __syncthreads();
#pragma unroll
    for (int i = 0; i < 4; i++) T[(w + 16 * i) * 64 + c] = accs[i];
    __syncthreads();
  }
#pragma unroll
  for (int i = 0; i < 4; i++) {
    const int r = w + 16 * i;
    A64[r * 64 + c] = T[r * 64 + c];
  }
}

// ---------- RMSNorm (row = 1024) -> bf16 ----------
__global__ __launch_bounds__(256) void rmsnorm_bf16(
    const float* __restrict__ x, const float* __restrict__ w,
    unsigned short* __restrict__ out) {
  const size_t row = blockIdx.x;
  const int tid = threadIdx.x;
  const float4 v = ((const float4*)(x + row * 1024))[tid];
  float ss = v.x * v.x + v.y * v.y + v.z * v.z + v.w * v.w;
#pragma unroll
  for (int off = 32; off > 0; off >>= 1) ss += __shfl_down(ss, off);
  __shared__ float wsum[4];
  if ((tid & 63) == 0) wsum[tid >> 6] = ss;
  __syncthreads();
  const float tot = wsum[0] + wsum[1] + wsum[2] + wsum[3];
  const float rs = rsqrtf(tot * (1.f / 1024.f) + 1e-6f);
  const float4 wv = ((const float4*)w)[tid];
  ushort4 o;
  o.x = f2b(v.x * rs * wv.x); o.y = f2b(v.y * rs * wv.y);
  o.z = f2b(v.z * rs * wv.z); o.w = f2b(v.w * rs * wv.w);
  ((ushort4*)(out + row * 1024))[tid] = o;
}

// ---------- RMSNorm (row = 1024) -> fp8 e4m3 ----------
__global__ __launch_bounds__(256) void rmsnorm_f8(
    const float* __restrict__ x, const float* __restrict__ w,
    unsigned int* __restrict__ out) {       // 4 fp8 per uint
  const size_t row = blockIdx.x;
  const int tid = threadIdx.x;
  const float4 v = ((const float4*)(x + row * 1024))[tid];
  float ss = v.x * v.x + v.y * v.y + v.z * v.z + v.w * v.w;
#pragma unroll
  for (int off = 32; off > 0; off >>= 1) ss += __shfl_down(ss, off);
  __shared__ float wsum[4];
  if ((tid & 63) == 0) wsum[tid >> 6] = ss;
  __syncthreads();
  const float tot = wsum[0] + wsum[1] + wsum[2] + wsum[3];
  const float rs = rsqrtf(tot * (1.f / 1024.f) + 1e-6f);
  const float4 wv = ((const float4*)w)[tid];
  out[row * 256 + tid] =
      f8pack4(v.x * rs * wv.x, v.y * rs * wv.y, v.z * rs * wv.z, v.w * rs * wv.w);
}

// ---------- scan (32 blocks, 4 chunk-waves each) + fp8 weight-convert riders ----------
template <int STORE_S>
__global__ __launch_bounds__(256) void scan_combo(
    const float* __restrict__ U, const float* __restrict__ Abar,
    const float* __restrict__ carry, float* __restrict__ zend,
    unsigned short* __restrict__ S,
    const float* __restrict__ csrc, unsigned char* __restrict__ cdst, size_t ccount) {
  constexpr int SCAN_BLOCKS = 32;
  __shared__ float s[4][64];
  if (blockIdx.x >= SCAN_BLOCKS) {
    size_t base = (size_t)(blockIdx.x - SCAN_BLOCKS) * 256 + threadIdx.x;
    size_t stride = (size_t)(gridDim.x - SCAN_BLOCKS) * 256;
    for (size_t id = base; id < ccount; id += stride)
      cdst[id] = f2f8(csrc[id] * 64.f);     // weights scaled x64 out of subnormal range
    return;
  }
  const int wave = threadIdx.x >> 6, i = threadIdx.x & 63;
  const int task = blockIdx.x * 4 + wave;
  const int b = task >> 5, c = task & 31;
  float a[64];
#pragma unroll
  for (int j = 0; j < 64; j++) a[j] = Abar[i * 64 + j];
  float cur = STORE_S ? carry[(b * 32 + c) * 64 + i] : 0.f;
  const float* Ub = U + ((size_t)(b * 2048 + c * 64)) * 64;
  for (int t = 0; t < 64; t++) {
    s[wave][i] = cur;
    __syncthreads();
    const float u = Ub[t * 64 + i];
    const float4* s4 = (const float4*)s[wave];
    float a0 = u, a1 = 0.f, a2 = 0.f, a3 = 0.f;
#pragma unroll
    for (int j = 0; j < 16; j++) {
      float4 v = s4[j];
      a0 += a[4 * j + 0] * v.x; a1 += a[4 * j + 1] * v.y;
      a2 += a[4 * j + 2] * v.z; a3 += a[4 * j + 3] * v.w;
    }
    cur = (a0 + a1) + (a2 + a3);
    __syncthreads();
    if (STORE_S) S[((size_t)(b * 2048 + c * 64 + t)) * 64 + i] = f2b(cur);
  }
  if (!STORE_S) zend[(b * 32 + c) * 64 + i] = cur;
}

// ---------- carry recurrence (block 0) + fp8 weight-convert riders ----------
__global__ __launch_bounds__(256) void carry_combo(
    const float* __restrict__ zend, const float* __restrict__ A64,
    float* __restrict__ carry,
    const float* __restrict__ csrc, unsigned char* __restrict__ cdst, size_t ccount) {
  __shared__ float s[4][64];
  if (blockIdx.x != 0) {
    size_t base = (size_t)(blockIdx.x - 1) * 256 + threadIdx.x;
    size_t stride = (size_t)(gridDim.x - 1) * 256;
    for (size_t id = base; id < ccount; id += stride)
      cdst[id] = f2f8(csrc[id] * 64.f);
    return;
  }
  const int b = threadIdx.x >> 6, i = threadIdx.x & 63;
  float a[64];
#pragma unroll
  for (int j = 0; j < 64; j++) a[j] = A64[i * 64 + j];
  float cur = 0.f;
  for (int c = 0; c < 32; c++) {
    carry[(b * 32 + c) * 64 + i] = cur;
    s[b][i] = cur;
    __syncthreads();
    const float z = zend[(b * 32 + c) * 64 + i];
    const float4* s4 = (const float4*)s[b];
    float a0 = z, a1 = 0.f, a2 = 0.f, a3 = 0.f;
#pragma unroll
    for (int j = 0; j < 16; j++) {
      float4 v = s4[j];
      a0 += a[4 * j + 0] * v.x; a1 += a[4 * j + 1] * v.y;
      a2 += a[4 * j + 2] * v.z; a3 += a[4 * j + 3] * v.w;
    }
    cur = (a0 + a1) + (a2 + a3);
    __syncthreads();
  }
}

// ---------- bf16 MFMA GEMM:  C(M,N) = X(M,K) @ W(N,K)^T ----------
// EPI: 0 = fp32 store | 4 = acc + e_d[n]*bf(e_b) + e_f -> fp32
template <int BM, int BN, int WAVES_M, int WAVES_N, int EPI>
__global__ void __launch_bounds__(256) gemm_bt(
    const unsigned short* __restrict__ X, const unsigned short* __restrict__ W,
    int M, int N, int K,
    float* __restrict__ outf, const unsigned short* __restrict__ e_b,
    const float* __restrict__ e_f, const float* __restrict__ e_d) {
  constexpr int BK = 64;
  constexpr int SM = BM / WAVES_M, SN = BN / WAVES_N;
  constexpr int TM = SM / 16, TN = SN / 16;
  __shared__ unsigned short aT[BM * BK];
  __shared__ unsigned short bT[BN * BK];
  const int tid = threadIdx.x;
  const int lane = tid & 63, wave = tid >> 6;
  const int wm = wave / WAVES_N, wn = wave % WAVES_N;
  const int lm = lane & 15, quad = lane >> 4;
  const long bm0 = (long)blockIdx.y * BM;
  const long bn0 = (long)blockIdx.x * BN;
  const int wb = tid & ~63;

  f32x4 acc[TM][TN];
#pragma unroll
  for (int i = 0; i < TM; i++)
#pragma unroll
    for (int j = 0; j < TN; j++) acc[i][j] = (f32x4){0.f, 0.f, 0.f, 0.f};

  for (int k0 = 0; k0 < K; k0 += BK) {
#pragma unroll
    for (int it = 0; it < (BM * 8) / 256; ++it) {
      int slot = it * 256 + tid;
      int r = slot >> 3, cp = slot & 7, c = cp ^ (r & 7);
      async_ld16(X + (bm0 + r) * (long)K + k0 + c * 8, aT + (it * 256 + wb) * 8);
    }
#pragma unroll
    for (int it = 0; it < (BN * 8) / 256; ++it) {
      int slot = it * 256 + tid;
      int r = slot >> 3, cp = slot & 7, c = cp ^ (r & 7);
      async_ld16(W + (bn0 + r) * (long)K + k0 + c * 8, bT + (it * 256 + wb) * 8);
    }
    __syncthreads();
#pragma unroll
    for (int kk = 0; kk < BK; kk += 32) {
      const int cch = (kk >> 3) + quad;
      short8 af[TM], bf[TN];
#pragma unroll
      for (int i = 0; i < TM; i++) {
        int r = wm * SM + i * 16 + lm;
        af[i] = *(const short8*)(aT + (r * 8 + (cch ^ (r & 7))) * 8);
      }
#pragma unroll
      for (int j = 0; j < TN; j++) {
        int r = wn * SN + j * 16 + lm;
        bf[j] = *(const short8*)(bT + (r * 8 + (cch ^ (r & 7))) * 8);
      }
#pragma unroll
      for (int i = 0; i < TM; i++)
#pragma unroll
        for (int j = 0; j < TN; j++)
          acc[i][j] = __builtin_amdgcn_mfma_f32_16x16x32_bf16(af[i], bf[j], acc[i][j], 0, 0, 0);
    }
    __syncthreads();
  }
#pragma unroll
  for (int i = 0; i < TM; i++) {
#pragma unroll
    for (int j = 0; j < TN; j++) {
#pragma unroll
      for (int r = 0; r < 4; r++) {
        const long m = bm0 + wm * SM + i * 16 + quad * 4 + r;
        const long n = bn0 + wn * SN + j * 16 + lm;
        const long idx = m * N + n;
        const float v = acc[i][j][r];
        if (EPI == 0) outf[idx] = v;
        else if (EPI == 4) outf[idx] = v + e_d[n] * b2f(e_b[idx]) + e_f[idx];
      }
    }
  }
}

// ---------- fused gate+up fp8 GEMM: act = silu(X@Wg^T)*(X@Wu^T)*inv^2... -> fp8 ----------
// X fp8 raw; Wg/Wu fp8 scaled x64 -> gate = accg/64, up = accu/64.
__global__ void __launch_bounds__(256) gemm_gu(
    const unsigned char* __restrict__ X, const unsigned char* __restrict__ Wg,
    const unsigned char* __restrict__ Wu, int M, int N, int K,
    unsigned char* __restrict__ out8, float inv) {
  constexpr int BM = 128, BN = 64, BK = 64;
  constexpr int SM = 64, SN = 32, TM = 4, TN = 2;
  __shared__ unsigned char aT[BM * BK];   // 8 KB
  __shared__ unsigned char gT[BN * BK];   // 4 KB
  __shared__ unsigned char uT[BN * BK];   // 4 KB
  const int tid = threadIdx.x;
  const int lane = tid & 63, wave = tid >> 6;
  const int wm = wave >> 1, wn = wave & 1;
  const int lm = lane & 15, quad = lane >> 4;
  const long bm0 = (long)blockIdx.y * BM;
  const long bn0 = (long)blockIdx.x * BN;
  const int wb = tid & ~63;

  f32x4 accg[TM][TN], accu[TM][TN];
#pragma unroll
  for (int i = 0; i < TM; i++)
#pragma unroll
    for (int j = 0; j < TN; j++) {
      accg[i][j] = (f32x4){0.f, 0.f, 0.f, 0.f};
      accu[i][j] = (f32x4){0.f, 0.f, 0.f, 0.f};
    }

  for (int k0 = 0; k0 < K; k0 += BK) {
#pragma unroll
    for (int it = 0; it < 2; ++it) {       // A: 128 rows x 4 chunks(16B)
      int slot = it * 256 + tid;
      int r = slot >> 2, cp = slot & 3, c = cp ^ ((r + (r >> 2)) & 3);
      async_ld16(X + (bm0 + r) * (long)K + k0 + c * 16, aT + (it * 256 + wb) * 16);
    }
    {                                      // Wg: 64 rows x 4 chunks
      int r = tid >> 2, cp = tid & 3, c = cp ^ ((r + (r >> 2)) & 3);
      async_ld16(Wg + (bn0 + r) * (long)K + k0 + c * 16, gT + wb * 16);
    }
    {                                      // Wu
      int r = tid >> 2, cp = tid & 3, c = cp ^ ((r + (r >> 2)) & 3);
      async_ld16(Wu + (bn0 + r) * (long)K + k0 + c * 16, uT + wb * 16);
    }
    __syncthreads();
#pragma unroll
    for (int kk = 0; kk < BK; kk += 32) {
      const int cc = (kk >> 4) + (quad >> 1);
      const int half = (quad & 1) * 8;
      long af[TM], gf[TN], uf[TN];
#pragma unroll
      for (int i = 0; i < TM; i++) {
        int r = wm * SM + i * 16 + lm;
        af[i] = *(const long*)(aT + (r * 4 + (cc ^ ((r + (r >> 2)) & 3))) * 16 + half);
      }
#pragma unroll
      for (int j = 0; j < TN; j++) {
        int r = wn * SN + j * 16 + lm;
        gf[j] = *(const long*)(gT + (r * 4 + (cc ^ ((r + (r >> 2)) & 3))) * 16 + half);
        uf[j] = *(const long*)(uT + (r * 4 + (cc ^ ((r + (r >> 2)) & 3))) * 16 + half);
      }
#pragma unroll
      for (int i = 0; i < TM; i++)
#pragma unroll
        for (int j = 0; j < TN; j++) {
          accg[i][j] = __builtin_amdgcn_mfma_f32_16x16x32_fp8_fp8(af[i], gf[j], accg[i][j], 0, 0, 0);
          accu[i][j] = __builtin_amdgcn_mfma_f32_16x16x32_fp8_fp8(af[i], uf[j], accu[i][j], 0, 0, 0);
        }
    }
    __syncthreads();
  }
#pragma unroll
  for (int i = 0; i < TM; i++) {
#pragma unroll
    for (int j = 0; j < TN; j++) {
#pragma unroll
      for (int r = 0; r < 4; r++) {
        const long m = bm0 + wm * SM + i * 16 + quad * 4 + r;
        const long n = bn0 + wn * SN + j * 16 + lm;
        const float g = accg[i][j][r] * inv;
        const float u = accu[i][j][r] * inv;
        const float s = g / (1.f + __expf(-g));
        out8[m * N + n] = f2f8(s * u);
      }
    }
  }
}

// ---------- fp8 MFMA GEMM (down proj): out = (X8 @ W8^T)*inv + e_f ----------
__global__ void __launch_bounds__(256) gemm_f8(
    const unsigned char* __restrict__ X, const unsigned char* __restrict__ W,
    int M, int N, int K,
    float* __restrict__ outf, const float* __restrict__ e_f, float inv) {
  constexpr int BM = 128, BN = 64, BK = 64;
  constexpr int SM = 64, SN = 32, TM = 4, TN = 2;
  __shared__ unsigned char aT[BM * BK];
  __shared__ unsigned char bT[BN * BK];
  const int tid = threadIdx.x;
  const int lane = tid & 63, wave = tid >> 6;
  const int wm = wave >> 1, wn = wave & 1;
  const int lm = lane & 15, quad = lane >> 4;
  const long bm0 = (long)blockIdx.y * BM;
  const long bn0 = (long)blockIdx.x * BN;
  const int wb = tid & ~63;

  f32x4 acc[TM][TN];
#pragma unroll
  for (int i = 0; i < TM; i++)
#pragma unroll
    for (int j = 0; j < TN; j++) acc[i][j] = (f32x4){0.f, 0.f, 0.f, 0.f};

  for (int k0 = 0; k0 < K; k0 += BK) {
#pragma unroll
    for (int it = 0; it < 2; ++it) {
      int slot = it * 256 + tid;
      int r = slot >> 2, cp = slot & 3, c = cp ^ ((r + (r >> 2)) & 3);
      async_ld16(X + (bm0 + r) * (long)K + k0 + c * 16, aT + (it * 256 + wb) * 16);
    }
    {
      int r = tid >> 2, cp = tid & 3, c = cp ^ ((r + (r >> 2)) & 3);
      async_ld16(W + (bn0 + r) * (long)K + k0 + c * 16, bT + wb * 16);
    }
    __syncthreads();
#pragma unroll
    for (int kk = 0; kk < BK; kk += 32) {
      const int cc = (kk >> 4) + (quad >> 1);
      const int half = (quad & 1) * 8;
      long af[TM], bf[TN];
#pragma unroll
      for (int i = 0; i < TM; i++) {
        int r = wm * SM + i * 16 + lm;
        af[i] = *(const long*)(aT + (r * 4 + (cc ^ ((r + (r >> 2)) & 3))) * 16 + half);
      }
#pragma unroll
      for (int j = 0; j < TN; j++) {
        int r = wn * SN + j * 16 + lm;
        bf[j] = *(const long*)(bT + (r * 4 + (cc ^ ((r + (r >> 2)) & 3))) * 16 + half);
      }
#pragma unroll
      for (int i = 0; i < TM; i++)
#pragma unroll
        for (int j = 0; j < TN; j++)
          acc[i][j] = __builtin_amdgcn_mfma_f32_16x16x32_fp8_fp8(af[i], bf[j], acc[i][j], 0, 0, 0);
    }
    __syncthreads();
  }
#pragma unroll
  for (int i = 0; i < TM; i++) {
#pragma unroll
    for (int j = 0; j < TN; j++) {
#pragma unroll
      for (int r = 0; r < 4; r++) {
        const long m = bm0 + wm * SM + i * 16 + quad * 4 + r;
        const long n = bn0 + wn * SN + j * 16 + lm;
        const long idx = m * N + n;
        outf[idx] = acc[i][j][r] * inv + e_f[idx];
      }
    }
  }
}

// ---------- launch ----------
extern "C" void kernel_launch(void* const* d_in, const int* in_sizes, int n_in,
                              void* d_out, int out_size, void* d_ws, size_t ws_size,
                              hipStream_t stream) {
  const float* x     = (const float*)d_in[0];   // (4,2048,1024)
  const float* A     = (const float*)d_in[1];   // (64,64)
  const float* B     = (const float*)d_in[2];   // (64,1024)
  const float* C     = (const float*)d_in[3];   // (1024,64)
  const float* D     = (const float*)d_in[4];   // (1024,)
  const float* logdt = (const float*)d_in[5];   // (1024,)
  const float* wg    = (const float*)d_in[6];   // (4096,1024)
  const float* wu    = (const float*)d_in[7];   // (4096,1024)
  const float* wd    = (const float*)d_in[8];   // (1024,4096)
  const float* ln1   = (const float*)d_in[9];
  const float* ln2   = (const float*)d_in[10];
  float* out = (float*)d_out;

  char* p = (char*)d_ws;
  auto alloc = [&](size_t bytes) { char* q = p; p += (bytes + 255) & ~(size_t)255; return q; };
  float* Abar  = (float*)alloc(64 * 64 * 4);
  float* A64   = (float*)alloc(64 * 64 * 4);
  float* zend  = (float*)alloc(4 * 32 * 64 * 4);
  float* carry = (float*)alloc(4 * 32 * 64 * 4);
  float* U     = (float*)alloc((size_t)8192 * 64 * 4);
  unsigned short* S    = (unsigned short*)alloc((size_t)8192 * 64 * 2);
  unsigned short* Bb   = (unsigned short*)alloc((size_t)64 * 1024 * 2);
  unsigned short* Cb   = (unsigned short*)alloc((size_t)1024 * 64 * 2);
  unsigned char*  wg8  = (unsigned char*)alloc((size_t)4096 * 1024);
  unsigned char*  wu8  = (unsigned char*)alloc((size_t)4096 * 1024);
  unsigned char*  wd8  = (unsigned char*)alloc((size_t)1024 * 4096);
  unsigned short* xnb  = (unsigned short*)alloc((size_t)8192 * 1024 * 2);
  unsigned char*  hn8  = (unsigned char*)alloc((size_t)8192 * 1024);
  float* h             = (float*)alloc((size_t)8192 * 1024 * 4);
  unsigned char*  act8 = (unsigned char*)alloc((size_t)8192 * 4096);

  const size_t NWG = (size_t)4096 * 1024;

  prep_combo<<<33, 1024, 0, stream>>>(A, logdt, Abar, A64, B, C, Bb, Cb);
  rmsnorm_bf16<<<8192, 256, 0, stream>>>(x, ln1, xnb);
  // U = xn @ B_bar^T
  gemm_bt<32, 64, 2, 2, 0><<<dim3(1, 256), 256, 0, stream>>>(
      xnb, Bb, 8192, 64, 1024, U, nullptr, nullptr, nullptr);
  // scan pass 1 (zero-init, chunk ends) + wg*64->fp8 convert
  scan_combo<0><<<32 + 1024, 256, 0, stream>>>(
      U, Abar, nullptr, zend, S, wg, wg8, NWG);
  // carry recurrence + wu*64->fp8 convert
  carry_combo<<<1 + 1024, 256, 0, stream>>>(zend, A64, carry, wu, wu8, NWG);
  // scan pass 2 (carry-init, all states bf16) + wd*64->fp8 convert
  scan_combo<1><<<32 + 1024, 256, 0, stream>>>(
      U, Abar, carry, zend, S, wd, wd8, NWG);
  // h = S @ C^T + D*xn + x
  gemm_bt<128, 128, 2, 2, 4><<<dim3(8, 64), 256, 0, stream>>>(
      S, Cb, 8192, 1024, 64, h, xnb, x, D);
  rmsnorm_f8<<<8192, 256, 0, stream>>>(h, ln2, (unsigned int*)hn8);
  // act = silu(hn @ wg^T / 64) * (hn @ wu^T / 64) -> fp8
  gemm_gu<<<dim3(64, 64), 256, 0, stream>>>(
      hn8, wg8, wu8, 8192, 4096, 1024, act8, 1.f / 64.f);
  // out = h + (act8 @ wd8^T)/64
  gemm_f8<<<dim3(16, 64), 256, 0, stream>>>(
      act8, wd8, 8192, 1024, 4096, out, h, 1.f / 64.f);
}

// Round 6
// 433.743 us; speedup vs baseline: 1.8264x; 1.1681x over previous
//
#include <hip/hip_runtime.h>
#include <hip/hip_bf16.h>
#include <math.h>

// ---------- helpers ----------
typedef __attribute__((ext_vector_type(8))) short short8;   // 8 bf16 = 4 VGPR (MFMA A/B frag)
typedef __attribute__((ext_vector_type(4))) float f32x4;    // MFMA C/D frag
typedef __attribute__((ext_vector_type(4))) int int4v;
typedef __attribute__((ext_vector_type(8))) int int8v;

__device__ __forceinline__ unsigned short f2b(float x) {    // fp32 -> bf16 bits, RNE
  union { float f; unsigned int u; } v; v.f = x;
  unsigned int r = v.u + 0x7fffu + ((v.u >> 16) & 1u);
  return (unsigned short)(r >> 16);
}
__device__ __forceinline__ float b2f(unsigned short u) {
  union { unsigned int u; float f; } v; v.u = ((unsigned int)u) << 16;
  return v.f;
}
// fp32 -> OCP e4m3fn byte (software fallback), RNE
__device__ __forceinline__ unsigned char f2f8_sw(float x) {
  float a = fabsf(x);
  unsigned char s = (x < 0.f) ? 0x80 : 0x00;
  if (a >= 464.f) return s | 0x7E;
  union { float f; unsigned u; } v; v.f = a;
  int e = (int)(v.u >> 23) - 127;
  if (e < -6) {
    int q = (int)rintf(a * 512.f);
    if (q >= 8) return s | 0x08;
    return s | (unsigned char)q;
  }
  unsigned mant = v.u & 0x7FFFFF;
  unsigned keep = mant >> 20;
  unsigned rest = mant & 0xFFFFF;
  if (rest > 0x80000u || (rest == 0x80000u && (keep & 1))) keep++;
  unsigned exp8 = (unsigned)(e + 7);
  if (keep == 8) { keep = 0; exp8++; }
  if (exp8 >= 15 && keep >= 7) return s | 0x7E;
  return s | (unsigned char)((exp8 << 3) | keep);
}
#if __has_builtin(__builtin_amdgcn_cvt_pk_fp8_f32)
__device__ __forceinline__ unsigned char f2f8(float x) {
  return (unsigned char)(__builtin_amdgcn_cvt_pk_fp8_f32(x, x, 0, false) & 0xFF);
}
__device__ __forceinline__ unsigned int f8pack4(float a, float b, float c, float d) {
  int w0 = __builtin_amdgcn_cvt_pk_fp8_f32(a, b, 0, false);
  return (unsigned int)__builtin_amdgcn_cvt_pk_fp8_f32(c, d, w0, true);
}
#else
__device__ __forceinline__ unsigned char f2f8(float x) { return f2f8_sw(x); }
__device__ __forceinline__ unsigned int f8pack4(float a, float b, float c, float d) {
  return (unsigned)f2f8_sw(a) | ((unsigned)f2f8_sw(b) << 8) |
         ((unsigned)f2f8_sw(c) << 16) | ((unsigned)f2f8_sw(d) << 24);
}
#endif
__device__ __forceinline__ void async_ld16(const void* g, void* l) {
  __builtin_amdgcn_global_load_lds(
      (const __attribute__((address_space(1))) void*)g,
      (__attribute__((address_space(3))) void*)l, 16, 0, 0);
}

// MX-scaled fp8 K=128 MFMA with unit scales (== exact fp8 GEMM at 2x rate).
// Fallback: 4x K=32 fp8 MFMAs over the same 32B fragments (identical math).
__device__ __forceinline__ f32x4 mx_fp8(int4v alo, int4v ahi, int4v blo, int4v bhi, f32x4 c) {
#if __has_builtin(__builtin_amdgcn_mfma_scale_f32_16x16x128_f8f6f4)
  int8v a = __builtin_shufflevector(alo, ahi, 0, 1, 2, 3, 4, 5, 6, 7);
  int8v b = __builtin_shufflevector(blo, bhi, 0, 1, 2, 3, 4, 5, 6, 7);
  return __builtin_amdgcn_mfma_scale_f32_16x16x128_f8f6f4(
      a, b, c, 0, 0, 0, 0x7F7F7F7F, 0, 0x7F7F7F7F);
#else
  int4v av[2] = {alo, ahi}, bv[2] = {blo, bhi};
  const long* al = (const long*)av;
  const long* bl = (const long*)bv;
#pragma unroll
  for (int j = 0; j < 4; j++)
    c = __builtin_amdgcn_mfma_f32_16x16x32_fp8_fp8(al[j], bl[j], c, 0, 0, 0);
  return c;
#endif
}

// ---------- prep (block 0) + Bb/Cb bf16 conversion (blocks 1..) ----------
__global__ __launch_bounds__(1024) void prep_combo(
    const float* __restrict__ A, const float* __restrict__ logdt,
    float* __restrict__ Abar, float* __restrict__ A64,
    const float* __restrict__ B, const float* __restrict__ Cm,
    unsigned short* __restrict__ Bb, unsigned short* __restrict__ Cb) {
  __shared__ float red[16];
  __shared__ float Ms[4096], T[4096], P[4096];
  if (blockIdx.x != 0) {
    const size_t NB = 65536, NC = 65536;
    size_t base = (size_t)(blockIdx.x - 1) * 1024 + threadIdx.x;
    size_t stride = (size_t)(gridDim.x - 1) * 1024;
    for (size_t id = base; id < NB + NC; id += stride) {
      if (id < NB) { int k = (int)(id & 1023); Bb[id] = f2b(B[id] * expf(logdt[k])); }
      else Cb[id - NB] = f2b(Cm[id - NB]);
    }
    return;
  }
  const int tid = threadIdx.x;
  const int c = tid & 63;
  const int w = tid >> 6;
  float e = expf(logdt[tid]);
#pragma unroll
  for (int off = 32; off > 0; off >>= 1) e += __shfl_down(e, off);
  if (c == 0) red[w] = e;
  __syncthreads();
  if (tid == 0) {
    float s = 0.f;
    for (int i = 0; i < 16; i++) s += red[i];
    red[0] = s * (1.f / 1024.f);
  }
  __syncthreads();
  const float mdt = red[0];
  {
    float m0 = A[tid] * mdt, m1 = A[tid + 1024] * mdt,
          m2 = A[tid + 2048] * mdt, m3 = A[tid + 3072] * mdt;
    Ms[tid] = m0; Ms[tid + 1024] = m1; Ms[tid + 2048] = m2; Ms[tid + 3072] = m3;
    T[tid] = m0; T[tid + 1024] = m1; T[tid + 2048] = m2; T[tid + 3072] = m3;
    P[tid] = m0 + ((tid >> 6) == (tid & 63) ? 1.f : 0.f);
    P[tid + 1024] = m1 + (((tid + 1024) >> 6) == ((tid + 1024) & 63) ? 1.f : 0.f);
    P[tid + 2048] = m2 + (((tid + 2048) >> 6) == ((tid + 2048) & 63) ? 1.f : 0.f);
    P[tid + 3072] = m3 + (((tid + 3072) >> 6) == ((tid + 3072) & 63) ? 1.f : 0.f);
  }
  __syncthreads();
  float colM[64];
#pragma unroll
  for (int j = 0; j < 64; j++) colM[j] = Ms[j * 64 + c];
  for (int k = 2; k <= 6; k++) {
    const float inv = 1.f / (float)k;
    float accs[4];
#pragma unroll
    for (int i = 0; i < 4; i++) {
      const int r = w + 16 * i;
      const float4* Trow = (const float4*)(T + r * 64);
      float a0 = 0.f, a1 = 0.f, a2 = 0.f, a3 = 0.f;
#pragma unroll
      for (int j4 = 0; j4 < 16; j4++) {
        const float4 t = Trow[j4];
        a0 += t.x * colM[4 * j4 + 0]; a1 += t.y * colM[4 * j4 + 1];
        a2 += t.z * colM[4 * j4 + 2]; a3 += t.w * colM[4 * j4 + 3];
      }
      accs[i] = ((a0 + a1) + (a2 + a3)) * inv;
    }
    __syncthreads();
#pragma unroll
    for (int i = 0; i < 4; i++) {
      const int r = w + 16 * i;
      T[r * 64 + c] = accs[i];
      P[r * 64 + c] += accs[i];
    }
    __syncthreads();
  }
#pragma unroll
  for (int i = 0; i < 4; i++) {
    const int r = w + 16 * i;
    Abar[r * 64 + c] = P[r * 64 + c];
    T[r * 64 + c] = P[r * 64 + c];
  }
  __syncthreads();
  for (int sq = 0; sq < 6; sq++) {
    float colT[64];
#pragma unroll
    for (int j = 0; j < 64; j++) colT[j] = T[j * 64 + c];
    float accs[4];
#pragma unroll
    for (int i = 0; i < 4; i++) {
      const int r = w + 16 * i;
      const float4* Trow = (const float4*)(T + r * 64);
      float a0 = 0.f, a1 = 0.f, a2 = 0.f, a3 = 0.f;
#pragma unroll
      for (int j4 = 0; j4 < 16; j4++) {
        const float4 t = Trow[j4];
        a0 += t.x * colT[4 * j4 + 0]; a1 += t.y * colT[4 * j4 + 1];
        a2 += t.z * colT[4 * j4 + 2]; a3 += t.w * colT[4 * j4 + 3];
      }
      accs[i] = (a0 + a1) + (a2 + a3);
    }
    __syncthreads();
#pragma unroll
    for (int i = 0; i < 4; i++) T[(w + 16 * i) * 64 + c] = accs[i];
    __syncthreads();
  }
#pragma unroll
  for (int i = 0; i < 4; i++) {
    const int r = w + 16 * i;
    A64[r * 64 + c] = T[r * 64 + c];
  }
}

// ---------- RMSNorm (row = 1024) -> bf16 ----------
__global__ __launch_bounds__(256) void rmsnorm_bf16(
    const float* __restrict__ x, const float* __restrict__ w,
    unsigned short* __restrict__ out) {
  const size_t row = blockIdx.x;
  const int tid = threadIdx.x;
  const float4 v = ((const float4*)(x + row * 1024))[tid];
  float ss = v.x * v.x + v.y * v.y + v.z * v.z + v.w * v.w;
#pragma unroll
  for (int off = 32; off > 0; off >>= 1) ss += __shfl_down(ss, off);
  __shared__ float wsum[4];
  if ((tid & 63) == 0) wsum[tid >> 6] = ss;
  __syncthreads();
  const float tot = wsum[0] + wsum[1] + wsum[2] + wsum[3];
  const float rs = rsqrtf(tot * (1.f / 1024.f) + 1e-6f);
  const float4 wv = ((const float4*)w)[tid];
  ushort4 o;
  o.x = f2b(v.x * rs * wv.x); o.y = f2b(v.y * rs * wv.y);
  o.z = f2b(v.z * rs * wv.z); o.w = f2b(v.w * rs * wv.w);
  ((ushort4*)(out + row * 1024))[tid] = o;
}

// ---------- RMSNorm (row = 1024) -> fp8 e4m3 ----------
__global__ __launch_bounds__(256) void rmsnorm_f8(
    const float* __restrict__ x, const float* __restrict__ w,
    unsigned int* __restrict__ out) {       // 4 fp8 per uint
  const size_t row = blockIdx.x;
  const int tid = threadIdx.x;
  const float4 v = ((const float4*)(x + row * 1024))[tid];
  float ss = v.x * v.x + v.y * v.y + v.z * v.z + v.w * v.w;
#pragma unroll
  for (int off = 32; off > 0; off >>= 1) ss += __shfl_down(ss, off);
  __shared__ float wsum[4];
  if ((tid & 63) == 0) wsum[tid >> 6] = ss;
  __syncthreads();
  const float tot = wsum[0] + wsum[1] + wsum[2] + wsum[3];
  const float rs = rsqrtf(tot * (1.f / 1024.f) + 1e-6f);
  const float4 wv = ((const float4*)w)[tid];
  out[row * 256 + tid] =
      f8pack4(v.x * rs * wv.x, v.y * rs * wv.y, v.z * rs * wv.z, v.w * rs * wv.w);
}

// ---------- scan (32 blocks, 4 chunk-waves each) + fp8 weight-convert riders ----------
template <int STORE_S>
__global__ __launch_bounds__(256) void scan_combo(
    const float* __restrict__ U, const float* __restrict__ Abar,
    const float* __restrict__ carry, float* __restrict__ zend,
    unsigned short* __restrict__ S,
    const float* __restrict__ csrc, unsigned char* __restrict__ cdst, size_t ccount) {
  constexpr int SCAN_BLOCKS = 32;
  __shared__ float s[4][64];
  if (blockIdx.x >= SCAN_BLOCKS) {
    size_t base = (size_t)(blockIdx.x - SCAN_BLOCKS) * 256 + threadIdx.x;
    size_t stride = (size_t)(gridDim.x - SCAN_BLOCKS) * 256;
    for (size_t id = base; id < ccount; id += stride)
      cdst[id] = f2f8(csrc[id] * 64.f);     // weights scaled x64 out of subnormal range
    return;
  }
  const int wave = threadIdx.x >> 6, i = threadIdx.x & 63;
  const int task = blockIdx.x * 4 + wave;
  const int b = task >> 5, c = task & 31;
  float a[64];
#pragma unroll
  for (int j = 0; j < 64; j++) a[j] = Abar[i * 64 + j];
  float cur = STORE_S ? carry[(b * 32 + c) * 64 + i] : 0.f;
  const float* Ub = U + ((size_t)(b * 2048 + c * 64)) * 64;
  for (int t = 0; t < 64; t++) {
    s[wave][i] = cur;
    __syncthreads();
    const float u = Ub[t * 64 + i];
    const float4* s4 = (const float4*)s[wave];
    float a0 = u, a1 = 0.f, a2 = 0.f, a3 = 0.f;
#pragma unroll
    for (int j = 0; j < 16; j++) {
      float4 v = s4[j];
      a0 += a[4 * j + 0] * v.x; a1 += a[4 * j + 1] * v.y;
      a2 += a[4 * j + 2] * v.z; a3 += a[4 * j + 3] * v.w;
    }
    cur = (a0 + a1) + (a2 + a3);
    __syncthreads();
    if (STORE_S) S[((size_t)(b * 2048 + c * 64 + t)) * 64 + i] = f2b(cur);
  }
  if (!STORE_S) zend[(b * 32 + c) * 64 + i] = cur;
}

// ---------- carry recurrence (block 0) + fp8 weight-convert riders ----------
__global__ __launch_bounds__(256) void carry_combo(
    const float* __restrict__ zend, const float* __restrict__ A64,
    float* __restrict__ carry,
    const float* __restrict__ csrc, unsigned char* __restrict__ cdst, size_t ccount) {
  __shared__ float s[4][64];
  if (blockIdx.x != 0) {
    size_t base = (size_t)(blockIdx.x - 1) * 256 + threadIdx.x;
    size_t stride = (size_t)(gridDim.x - 1) * 256;
    for (size_t id = base; id < ccount; id += stride)
      cdst[id] = f2f8(csrc[id] * 64.f);
    return;
  }
  const int b = threadIdx.x >> 6, i = threadIdx.x & 63;
  float a[64];
#pragma unroll
  for (int j = 0; j < 64; j++) a[j] = A64[i * 64 + j];
  float cur = 0.f;
  for (int c = 0; c < 32; c++) {
    carry[(b * 32 + c) * 64 + i] = cur;
    s[b][i] = cur;
    __syncthreads();
    const float z = zend[(b * 32 + c) * 64 + i];
    const float4* s4 = (const float4*)s[b];
    float a0 = z, a1 = 0.f, a2 = 0.f, a3 = 0.f;
#pragma unroll
    for (int j = 0; j < 16; j++) {
      float4 v = s4[j];
      a0 += a[4 * j + 0] * v.x; a1 += a[4 * j + 1] * v.y;
      a2 += a[4 * j + 2] * v.z; a3 += a[4 * j + 3] * v.w;
    }
    cur = (a0 + a1) + (a2 + a3);
    __syncthreads();
  }
}

// ---------- bf16 MFMA GEMM:  C(M,N) = X(M,K) @ W(N,K)^T ----------
// EPI: 0 = fp32 store | 4 = acc + e_d[n]*bf(e_b) + e_f -> fp32
template <int BM, int BN, int WAVES_M, int WAVES_N, int EPI>
__global__ void __launch_bounds__(256) gemm_bt(
    const unsigned short* __restrict__ X, const unsigned short* __restrict__ W,
    int M, int N, int K,
    float* __restrict__ outf, const unsigned short* __restrict__ e_b,
    const float* __restrict__ e_f, const float* __restrict__ e_d) {
  constexpr int BK = 64;
  constexpr int SM = BM / WAVES_M, SN = BN / WAVES_N;
  constexpr int TM = SM / 16, TN = SN / 16;
  __shared__ unsigned short aT[BM * BK];
  __shared__ unsigned short bT[BN * BK];
  const int tid = threadIdx.x;
  const int lane = tid & 63, wave = tid >> 6;
  const int wm = wave / WAVES_N, wn = wave % WAVES_N;
  const int lm = lane & 15, quad = lane >> 4;
  const long bm0 = (long)blockIdx.y * BM;
  const long bn0 = (long)blockIdx.x * BN;
  const int wb = tid & ~63;

  f32x4 acc[TM][TN];
#pragma unroll
  for (int i = 0; i < TM; i++)
#pragma unroll
    for (int j = 0; j < TN; j++) acc[i][j] = (f32x4){0.f, 0.f, 0.f, 0.f};

  for (int k0 = 0; k0 < K; k0 += BK) {
#pragma unroll
    for (int it = 0; it < (BM * 8) / 256; ++it) {
      int slot = it * 256 + tid;
      int r = slot >> 3, cp = slot & 7, c = cp ^ (r & 7);
      async_ld16(X + (bm0 + r) * (long)K + k0 + c * 8, aT + (it * 256 + wb) * 8);
    }
#pragma unroll
    for (int it = 0; it < (BN * 8) / 256; ++it) {
      int slot = it * 256 + tid;
      int r = slot >> 3, cp = slot & 7, c = cp ^ (r & 7);
      async_ld16(W + (bn0 + r) * (long)K + k0 + c * 8, bT + (it * 256 + wb) * 8);
    }
    __syncthreads();
#pragma unroll
    for (int kk = 0; kk < BK; kk += 32) {
      const int cch = (kk >> 3) + quad;
      short8 af[TM], bf[TN];
#pragma unroll
      for (int i = 0; i < TM; i++) {
        int r = wm * SM + i * 16 + lm;
        af[i] = *(const short8*)(aT + (r * 8 + (cch ^ (r & 7))) * 8);
      }
#pragma unroll
      for (int j = 0; j < TN; j++) {
        int r = wn * SN + j * 16 + lm;
        bf[j] = *(const short8*)(bT + (r * 8 + (cch ^ (r & 7))) * 8);
      }
#pragma unroll
      for (int i = 0; i < TM; i++)
#pragma unroll
        for (int j = 0; j < TN; j++)
          acc[i][j] = __builtin_amdgcn_mfma_f32_16x16x32_bf16(af[i], bf[j], acc[i][j], 0, 0, 0);
    }
    __syncthreads();
  }
#pragma unroll
  for (int i = 0; i < TM; i++) {
#pragma unroll
    for (int j = 0; j < TN; j++) {
#pragma unroll
      for (int r = 0; r < 4; r++) {
        const long m = bm0 + wm * SM + i * 16 + quad * 4 + r;
        const long n = bn0 + wn * SN + j * 16 + lm;
        const long idx = m * N + n;
        const float v = acc[i][j][r];
        if (EPI == 0) outf[idx] = v;
        else if (EPI == 4) outf[idx] = v + e_d[n] * b2f(e_b[idx]) + e_f[idx];
      }
    }
  }
}

// ---------- fused gate+up MX-fp8 GEMM (K=128/instr): act -> fp8 ----------
// X fp8 raw; Wg/Wu fp8 scaled x64 -> gate = accg/64, up = accu/64.
__global__ void __launch_bounds__(256) gemm_gu(
    const unsigned char* __restrict__ X, const unsigned char* __restrict__ Wg,
    const unsigned char* __restrict__ Wu, int M, int N, int K,
    unsigned char* __restrict__ out8, float inv) {
  constexpr int BM = 128, BN = 64, BK = 128;
  constexpr int TM = 4, TN = 2;
  __shared__ __attribute__((aligned(16))) unsigned char aT[BM * BK];  // 16 KB
  __shared__ __attribute__((aligned(16))) unsigned char gT[BN * BK];  // 8 KB
  __shared__ __attribute__((aligned(16))) unsigned char uT[BN * BK];  // 8 KB
  const int tid = threadIdx.x;
  const int lane = tid & 63, wave = tid >> 6;
  const int wm = wave >> 1, wn = wave & 1;
  const int lm = lane & 15, quad = lane >> 4;
  const long bm0 = (long)blockIdx.y * BM;
  const long bn0 = (long)blockIdx.x * BN;
  const int wb = tid & ~63;

  f32x4 accg[TM][TN], accu[TM][TN];
#pragma unroll
  for (int i = 0; i < TM; i++)
#pragma unroll
    for (int j = 0; j < TN; j++) {
      accg[i][j] = (f32x4){0.f, 0.f, 0.f, 0.f};
      accu[i][j] = (f32x4){0.f, 0.f, 0.f, 0.f};
    }

  for (int k0 = 0; k0 < K; k0 += BK) {
#pragma unroll
    for (int it = 0; it < 4; ++it) {       // A: 128 rows x 8 chunks(16B)
      int slot = it * 256 + tid;
      int r = slot >> 3, cp = slot & 7, c = cp ^ (r & 7);
      async_ld16(X + (bm0 + r) * (long)K + k0 + c * 16, aT + (it * 256 + wb) * 16);
    }
#pragma unroll
    for (int it = 0; it < 2; ++it) {       // Wg: 64 rows x 8 chunks
      int slot = it * 256 + tid;
      int r = slot >> 3, cp = slot & 7, c = cp ^ (r & 7);
      async_ld16(Wg + (bn0 + r) * (long)K + k0 + c * 16, gT + (it * 256 + wb) * 16);
    }
#pragma unroll
    for (int it = 0; it < 2; ++it) {       // Wu
      int slot = it * 256 + tid;
      int r = slot >> 3, cp = slot & 7, c = cp ^ (r & 7);
      async_ld16(Wu + (bn0 + r) * (long)K + k0 + c * 16, uT + (it * 256 + wb) * 16);
    }
    __syncthreads();
    int4v alo[TM], ahi[TM], glo[TN], ghi[TN], ulo[TN], uhi[TN];
#pragma unroll
    for (int i = 0; i < TM; i++) {
      int r = wm * 64 + i * 16 + lm;
      alo[i] = *(const int4v*)(aT + (r * 8 + ((2 * quad) ^ (r & 7))) * 16);
      ahi[i] = *(const int4v*)(aT + (r * 8 + ((2 * quad + 1) ^ (r & 7))) * 16);
    }
#pragma unroll
    for (int j = 0; j < TN; j++) {
      int r = wn * 32 + j * 16 + lm;
      glo[j] = *(const int4v*)(gT + (r * 8 + ((2 * quad) ^ (r & 7))) * 16);
      ghi[j] = *(const int4v*)(gT + (r * 8 + ((2 * quad + 1) ^ (r & 7))) * 16);
      ulo[j] = *(const int4v*)(uT + (r * 8 + ((2 * quad) ^ (r & 7))) * 16);
      uhi[j] = *(const int4v*)(uT + (r * 8 + ((2 * quad + 1) ^ (r & 7))) * 16);
    }
#pragma unroll
    for (int i = 0; i < TM; i++)
#pragma unroll
      for (int j = 0; j < TN; j++) {
        accg[i][j] = mx_fp8(alo[i], ahi[i], glo[j], ghi[j], accg[i][j]);
        accu[i][j] = mx_fp8(alo[i], ahi[i], ulo[j], uhi[j], accu[i][j]);
      }
    __syncthreads();
  }
#pragma unroll
  for (int i = 0; i < TM; i++) {
#pragma unroll
    for (int j = 0; j < TN; j++) {
#pragma unroll
      for (int r = 0; r < 4; r++) {
        const long m = bm0 + wm * 64 + i * 16 + quad * 4 + r;
        const long n = bn0 + wn * 32 + j * 16 + lm;
        const float g = accg[i][j][r] * inv;
        const float u = accu[i][j][r] * inv;
        const float s = g / (1.f + __expf(-g));
        out8[m * N + n] = f2f8(s * u);
      }
    }
  }
}

// ---------- MX-fp8 GEMM (down proj, K=128/instr): out = (X8 @ W8^T)*inv + e_f ----------
__global__ void __launch_bounds__(256) gemm_f8(
    const unsigned char* __restrict__ X, const unsigned char* __restrict__ W,
    int M, int N, int K,
    float* __restrict__ outf, const float* __restrict__ e_f, float inv) {
  constexpr int BM = 128, BN = 64, BK = 128;
  constexpr int TM = 4, TN = 2;
  __shared__ __attribute__((aligned(16))) unsigned char aT[BM * BK];  // 16 KB
  __shared__ __attribute__((aligned(16))) unsigned char bT[BN * BK];  // 8 KB
  const int tid = threadIdx.x;
  const int lane = tid & 63, wave = tid >> 6;
  const int wm = wave >> 1, wn = wave & 1;
  const int lm = lane & 15, quad = lane >> 4;
  const long bm0 = (long)blockIdx.y * BM;
  const long bn0 = (long)blockIdx.x * BN;
  const int wb = tid & ~63;

  f32x4 acc[TM][TN];
#pragma unroll
  for (int i = 0; i < TM; i++)
#pragma unroll
    for (int j = 0; j < TN; j++) acc[i][j] = (f32x4){0.f, 0.f, 0.f, 0.f};

  for (int k0 = 0; k0 < K; k0 += BK) {
#pragma unroll
    for (int it = 0; it < 4; ++it) {       // A: 128 rows x 8 chunks
      int slot = it * 256 + tid;
      int r = slot >> 3, cp = slot & 7, c = cp ^ (r & 7);
      async_ld16(X + (bm0 + r) * (long)K + k0 + c * 16, aT + (it * 256 + wb) * 16);
    }
#pragma unroll
    for (int it = 0; it < 2; ++it) {       // B: 64 rows x 8 chunks
      int slot = it * 256 + tid;
      int r = slot >> 3, cp = slot & 7, c = cp ^ (r & 7);
      async_ld16(W + (bn0 + r) * (long)K + k0 + c * 16, bT + (it * 256 + wb) * 16);
    }
    __syncthreads();
    int4v alo[TM], ahi[TM], blo[TN], bhi[TN];
#pragma unroll
    for (int i = 0; i < TM; i++) {
      int r = wm * 64 + i * 16 + lm;
      alo[i] = *(const int4v*)(aT + (r * 8 + ((2 * quad) ^ (r & 7))) * 16);
      ahi[i] = *(const int4v*)(aT + (r * 8 + ((2 * quad + 1) ^ (r & 7))) * 16);
    }
#pragma unroll
    for (int j = 0; j < TN; j++) {
      int r = wn * 32 + j * 16 + lm;
      blo[j] = *(const int4v*)(bT + (r * 8 + ((2 * quad) ^ (r & 7))) * 16);
      bhi[j] = *(const int4v*)(bT + (r * 8 + ((2 * quad + 1) ^ (r & 7))) * 16);
    }
#pragma unroll
    for (int i = 0; i < TM; i++)
#pragma unroll
      for (int j = 0; j < TN; j++)
        acc[i][j] = mx_fp8(alo[i], ahi[i], blo[j], bhi[j], acc[i][j]);
    __syncthreads();
  }
#pragma unroll
  for (int i = 0; i < TM; i++) {
#pragma unroll
    for (int j = 0; j < TN; j++) {
#pragma unroll
      for (int r = 0; r < 4; r++) {
        const long m = bm0 + wm * 64 + i * 16 + quad * 4 + r;
        const long n = bn0 + wn * 32 + j * 16 + lm;
        const long idx = m * N + n;
        outf[idx] = acc[i][j][r] * inv + e_f[idx];
      }
    }
  }
}

// ---------- launch ----------
extern "C" void kernel_launch(void* const* d_in, const int* in_sizes, int n_in,
                              void* d_out, int out_size, void* d_ws, size_t ws_size,
                              hipStream_t stream) {
  const float* x     = (const float*)d_in[0];   // (4,2048,1024)
  const float* A     = (const float*)d_in[1];   // (64,64)
  const float* B     = (const float*)d_in[2];   // (64,1024)
  const float* C     = (const float*)d_in[3];   // (1024,64)
  const float* D     = (const float*)d_in[4];   // (1024,)
  const float* logdt = (const float*)d_in[5];   // (1024,)
  const float* wg    = (const float*)d_in[6];   // (4096,1024)
  const float* wu    = (const float*)d_in[7];   // (4096,1024)
  const float* wd    = (const float*)d_in[8];   // (1024,4096)
  const float* ln1   = (const float*)d_in[9];
  const float* ln2   = (const float*)d_in[10];
  float* out = (float*)d_out;

  char* p = (char*)d_ws;
  auto alloc = [&](size_t bytes) { char* q = p; p += (bytes + 255) & ~(size_t)255; return q; };
  float* Abar  = (float*)alloc(64 * 64 * 4);
  float* A64   = (float*)alloc(64 * 64 * 4);
  float* zend  = (float*)alloc(4 * 32 * 64 * 4);
  float* carry = (float*)alloc(4 * 32 * 64 * 4);
  float* U     = (float*)alloc((size_t)8192 * 64 * 4);
  unsigned short* S    = (unsigned short*)alloc((size_t)8192 * 64 * 2);
  unsigned short* Bb   = (unsigned short*)alloc((size_t)64 * 1024 * 2);
  unsigned short* Cb   = (unsigned short*)alloc((size_t)1024 * 64 * 2);
  unsigned char*  wg8  = (unsigned char*)alloc((size_t)4096 * 1024);
  unsigned char*  wu8  = (unsigned char*)alloc((size_t)4096 * 1024);
  unsigned char*  wd8  = (unsigned char*)alloc((size_t)1024 * 4096);
  unsigned short* xnb  = (unsigned short*)alloc((size_t)8192 * 1024 * 2);
  unsigned char*  hn8  = (unsigned char*)alloc((size_t)8192 * 1024);
  float* h             = (float*)alloc((size_t)8192 * 1024 * 4);
  unsigned char*  act8 = (unsigned char*)alloc((size_t)8192 * 4096);

  const size_t NWG = (size_t)4096 * 1024;

  prep_combo<<<33, 1024, 0, stream>>>(A, logdt, Abar, A64, B, C, Bb, Cb);
  rmsnorm_bf16<<<8192, 256, 0, stream>>>(x, ln1, xnb);
  // U = xn @ B_bar^T
  gemm_bt<32, 64, 2, 2, 0><<<dim3(1, 256), 256, 0, stream>>>(
      xnb, Bb, 8192, 64, 1024, U, nullptr, nullptr, nullptr);
  // scan pass 1 (zero-init, chunk ends) + wg*64->fp8 convert
  scan_combo<0><<<32 + 1024, 256, 0, stream>>>(
      U, Abar, nullptr, zend, S, wg, wg8, NWG);
  // carry recurrence + wu*64->fp8 convert
  carry_combo<<<1 + 1024, 256, 0, stream>>>(zend, A64, carry, wu, wu8, NWG);
  // scan pass 2 (carry-init, all states bf16) + wd*64->fp8 convert
  scan_combo<1><<<32 + 1024, 256, 0, stream>>>(
      U, Abar, carry, zend, S, wd, wd8, NWG);
  // h = S @ C^T + D*xn + x
  gemm_bt<128, 128, 2, 2, 4><<<dim3(8, 64), 256, 0, stream>>>(
      S, Cb, 8192, 1024, 64, h, xnb, x, D);
  rmsnorm_f8<<<8192, 256, 0, stream>>>(h, ln2, (unsigned int*)hn8);
  // act = silu(hn @ wg^T / 64) * (hn @ wu^T / 64) -> fp8
  gemm_gu<<<dim3(64, 64), 256, 0, stream>>>(
      hn8, wg8, wu8, 8192, 4096, 1024, act8, 1.f / 64.f);
  // out = h + (act8 @ wd8^T)/64
  gemm_f8<<<dim3(16, 64), 256, 0, stream>>>(
      act8, wd8, 8192, 1024, 4096, out, h, 1.f / 64.f);
}